// Round 1
// baseline (32179.227 us; speedup 1.0000x reference)
//
#include <hip/hip_runtime.h>
#include <hip/hip_bf16.h>
#include <math.h>

#define L 2048
#define D 768
#define H 12
#define DH 64
#define F 3072
#define NL 12

// ---------------- position cumsum ----------------
__global__ void pos_kernel(const int* __restrict__ mask, int* __restrict__ pos) {
    __shared__ int sm[L];
    for (int i = threadIdx.x; i < L; i += blockDim.x) sm[i] = mask[i];
    __syncthreads();
    int t = blockIdx.x * blockDim.x + threadIdx.x;
    if (t < L) {
        int s = 0;
        for (int j = 0; j <= t; ++j) s += sm[j];
        int p = s - 1;
        if (sm[t] == 0) p = 1;
        pos[t] = p;
    }
}

// ---------------- embedding ----------------
__global__ __launch_bounds__(256) void embed_kernel(const int* __restrict__ ids,
                                                    const int* __restrict__ pos,
                                                    const float* __restrict__ wte,
                                                    const float* __restrict__ wpe,
                                                    float* __restrict__ h) {
    int t = blockIdx.x;
    int id = ids[t];
    int p = pos[t];
    const float* we = wte + (size_t)id * D;
    const float* wp = wpe + (size_t)p * D;
    float* hr = h + (size_t)t * D;
#pragma unroll
    for (int i = 0; i < 3; ++i) {
        int d = threadIdx.x + i * 256;
        hr[d] = we[d] + wp[d];
    }
}

// ---------------- layernorm ----------------
__global__ __launch_bounds__(256) void ln_kernel(const float* __restrict__ in,
                                                 const float* __restrict__ w,
                                                 const float* __restrict__ b,
                                                 float* __restrict__ out) {
    __shared__ float red[2][4];
    int row = blockIdx.x;
    const float* x = in + (size_t)row * D;
    int t = threadIdx.x;
    float v0 = x[t], v1 = x[t + 256], v2 = x[t + 512];
    float s = v0 + v1 + v2;
    float ss = v0 * v0 + v1 * v1 + v2 * v2;
#pragma unroll
    for (int o = 32; o; o >>= 1) {
        s += __shfl_xor(s, o);
        ss += __shfl_xor(ss, o);
    }
    int wave = t >> 6;
    if ((t & 63) == 0) { red[0][wave] = s; red[1][wave] = ss; }
    __syncthreads();
    s = red[0][0] + red[0][1] + red[0][2] + red[0][3];
    ss = red[1][0] + red[1][1] + red[1][2] + red[1][3];
    float mean = s * (1.f / D);
    float var = ss * (1.f / D) - mean * mean;
    float rstd = rsqrtf(var + 1e-5f);
    float* y = out + (size_t)row * D;
#pragma unroll
    for (int i = 0; i < 3; ++i) {
        int d = t + i * 256;
        float vv = (i == 0) ? v0 : (i == 1) ? v1 : v2;
        y[d] = (vv - mean) * rstd * w[d] + b[d];
    }
}

// ---------------- gelu ----------------
__device__ __forceinline__ float gelu_tanh(float x) {
    float c = 0.7978845608028654f;   // sqrt(2/pi)
    float inner = c * (x + 0.044715f * x * x * x);
    return 0.5f * x * (1.0f + tanhf(inner));
}

// ---------------- tiled f32 GEMM ----------------
// C[M,N] = act(A[M,K] @ B[K,N] + bias) + resid
// BM=BN=64, BK=16, 256 threads, 4x4 microtile.
template <int ACT>
__global__ __launch_bounds__(256) void gemm_kernel(const float* __restrict__ A,
                                                   const float* __restrict__ B,
                                                   const float* __restrict__ bias,
                                                   const float* __restrict__ resid,
                                                   float* __restrict__ C,
                                                   int M, int N, int K) {
    __shared__ __align__(16) float As[16][68];
    __shared__ __align__(16) float Bs[16][68];
    int bm = blockIdx.y * 64, bn = blockIdx.x * 64;
    int tid = threadIdx.x;
    int a_k = tid & 15;
    int a_r = tid >> 4;
    int b_n = tid & 63;
    int b_k = tid >> 6;
    int tx = tid & 15, ty = tid >> 4;
    float c[4][4] = {};
    for (int k0 = 0; k0 < K; k0 += 16) {
#pragma unroll
        for (int i = 0; i < 4; ++i)
            As[a_k][a_r + 16 * i] = A[(size_t)(bm + a_r + 16 * i) * K + k0 + a_k];
#pragma unroll
        for (int i = 0; i < 4; ++i)
            Bs[b_k + 4 * i][b_n] = B[(size_t)(k0 + b_k + 4 * i) * N + bn + b_n];
        __syncthreads();
#pragma unroll
        for (int kk = 0; kk < 16; ++kk) {
            float4 av = *reinterpret_cast<const float4*>(&As[kk][ty * 4]);
            float4 bv = *reinterpret_cast<const float4*>(&Bs[kk][tx * 4]);
            float a[4] = {av.x, av.y, av.z, av.w};
            float bb[4] = {bv.x, bv.y, bv.z, bv.w};
#pragma unroll
            for (int i = 0; i < 4; ++i)
#pragma unroll
                for (int j = 0; j < 4; ++j)
                    c[i][j] += a[i] * bb[j];
        }
        __syncthreads();
    }
#pragma unroll
    for (int i = 0; i < 4; ++i) {
        int m = bm + ty * 4 + i;
        int n0 = bn + tx * 4;
        float4 r;
        float vv[4];
#pragma unroll
        for (int j = 0; j < 4; ++j) {
            float v = c[i][j];
            if (bias) v += bias[n0 + j];
            if (ACT == 1) v = gelu_tanh(v);
            vv[j] = v;
        }
        if (resid) {
            float4 rv = *reinterpret_cast<const float4*>(&resid[(size_t)m * N + n0]);
            vv[0] += rv.x; vv[1] += rv.y; vv[2] += rv.z; vv[3] += rv.w;
        }
        r.x = vv[0]; r.y = vv[1]; r.z = vv[2]; r.w = vv[3];
        *reinterpret_cast<float4*>(&C[(size_t)m * N + n0]) = r;
    }
}

// ---------------- attention (one wave per head x query row) ----------------
__global__ __launch_bounds__(64) void attn_kernel(const float* __restrict__ q,
                                                  const float* __restrict__ k,
                                                  const float* __restrict__ v,
                                                  const int* __restrict__ mask,
                                                  float* __restrict__ ctx) {
    int t = blockIdx.x;
    int hh = blockIdx.y;
    int lane = threadIdx.x;
    float qd = q[(size_t)t * D + hh * DH + lane];
    float m = -1e30f, l = 0.f, acc = 0.f;
    for (int kk = 0; kk <= t; ++kk) {
        if (mask[kk] == 0) continue;
        float kd = k[(size_t)kk * D + hh * DH + lane];
        float s = qd * kd;
#pragma unroll
        for (int o = 32; o; o >>= 1) s += __shfl_xor(s, o);
        float vd = v[(size_t)kk * D + hh * DH + lane];
        float mn = fmaxf(m, s);
        float scale = __expf(m - mn);
        float p = __expf(s - mn);
        l = l * scale + p;
        acc = acc * scale + p * vd;
        m = mn;
    }
    ctx[(size_t)t * D + hh * DH + lane] = acc / l;
}

extern "C" void kernel_launch(void* const* d_in, const int* in_sizes, int n_in,
                              void* d_out, int out_size, void* d_ws, size_t ws_size,
                              hipStream_t stream) {
    const int* ids = (const int*)d_in[0];
    const int* amask = (const int*)d_in[1];
    const float* wte = (const float*)d_in[2];
    const float* wpe = (const float*)d_in[3];
    const float* lnf_w = (const float*)d_in[4];
    const float* lnf_b = (const float*)d_in[5];
    const float* ln1_w = (const float*)d_in[6];
    const float* ln1_b = (const float*)d_in[7];
    const float* qw = (const float*)d_in[8];
    const float* kw = (const float*)d_in[9];
    const float* vw = (const float*)d_in[10];
    const float* ow = (const float*)d_in[11];
    const float* ob = (const float*)d_in[12];
    const float* ln2_w = (const float*)d_in[13];
    const float* ln2_b = (const float*)d_in[14];
    const float* fcw = (const float*)d_in[15];
    const float* fcb = (const float*)d_in[16];
    const float* pw = (const float*)d_in[17];
    const float* pb = (const float*)d_in[18];

    const size_t MB8 = 8u * 1024u * 1024u;
    char* ws = (char*)d_ws;
    float* h   = (float*)(ws + 0 * MB8);
    float* x   = (float*)(ws + 1 * MB8);
    float* qb  = (float*)(ws + 2 * MB8);
    float* kb  = (float*)(ws + 3 * MB8);
    float* vb  = (float*)(ws + 4 * MB8);
    float* f1  = (float*)(ws + 2 * MB8);  // FFN intermediate aliases q/k/v (24 MB)
    float* cb  = x;                       // ctx aliases x (x dead after QKV)
    int* pos   = (int*)(ws + 5 * MB8);

    pos_kernel<<<8, 256, 0, stream>>>(amask, pos);
    embed_kernel<<<L, 256, 0, stream>>>(ids, pos, wte, wpe, h);

    for (int l = 0; l < NL; ++l) {
        ln_kernel<<<L, 256, 0, stream>>>(h, ln1_w + l * D, ln1_b + l * D, x);
        gemm_kernel<0><<<dim3(D / 64, L / 64), 256, 0, stream>>>(
            x, qw + (size_t)l * D * D, nullptr, nullptr, qb, L, D, D);
        gemm_kernel<0><<<dim3(D / 64, L / 64), 256, 0, stream>>>(
            x, kw + (size_t)l * D * D, nullptr, nullptr, kb, L, D, D);
        gemm_kernel<0><<<dim3(D / 64, L / 64), 256, 0, stream>>>(
            x, vw + (size_t)l * D * D, nullptr, nullptr, vb, L, D, D);
        attn_kernel<<<dim3(L, H), 64, 0, stream>>>(qb, kb, vb, amask, cb);
        gemm_kernel<0><<<dim3(D / 64, L / 64), 256, 0, stream>>>(
            cb, ow + (size_t)l * D * D, ob + l * D, h, h, L, D, D);
        ln_kernel<<<L, 256, 0, stream>>>(h, ln2_w + l * D, ln2_b + l * D, x);
        gemm_kernel<1><<<dim3(F / 64, L / 64), 256, 0, stream>>>(
            x, fcw + (size_t)l * D * F, fcb + l * F, nullptr, f1, L, F, D);
        gemm_kernel<0><<<dim3(D / 64, L / 64), 256, 0, stream>>>(
            f1, pw + (size_t)l * F * D, pb + l * D, h, h, L, D, F);
    }
    ln_kernel<<<L, 256, 0, stream>>>(h, lnf_w, lnf_b, (float*)d_out);
}

// Round 2
// 3765.260 us; speedup vs baseline: 8.5463x; 8.5463x over previous
//
#include <hip/hip_runtime.h>
#include <hip/hip_bf16.h>
#include <math.h>
#include <stdint.h>

#define L 2048
#define D 768
#define H 12
#define DH 64
#define F 3072
#define NL 12
#define QKVN 2304

typedef __attribute__((ext_vector_type(8))) short bf16x8;
typedef __attribute__((ext_vector_type(4))) float f32x4;

__device__ __forceinline__ ushort f2bf(float x) {
    union { float f; uint32_t u; } c; c.f = x;
    uint32_t r = c.u + 0x7FFFu + ((c.u >> 16) & 1u);
    return (ushort)(r >> 16);
}

// load one MFMA A/B fragment (16x16x32 bf16): elems 0-3 at p, 4-7 at p+16
__device__ __forceinline__ bf16x8 ldfrag(const ushort* p) {
    ushort4 lo = *(const ushort4*)(p);
    ushort4 hi = *(const ushort4*)(p + 16);
    bf16x8 f;
    f[0] = (short)lo.x; f[1] = (short)lo.y; f[2] = (short)lo.z; f[3] = (short)lo.w;
    f[4] = (short)hi.x; f[5] = (short)hi.y; f[6] = (short)hi.z; f[7] = (short)hi.w;
    return f;
}

__device__ __forceinline__ float gelu_tanh(float x) {
    float c = 0.7978845608028654f;
    float inner = c * (x + 0.044715f * x * x * x);
    return 0.5f * x * (1.0f + tanhf(inner));
}

// ---------------- position cumsum ----------------
__global__ void pos_kernel(const int* __restrict__ mask, int* __restrict__ pos) {
    __shared__ int sm[L];
    for (int i = threadIdx.x; i < L; i += blockDim.x) sm[i] = mask[i];
    __syncthreads();
    int t = blockIdx.x * blockDim.x + threadIdx.x;
    if (t < L) {
        int s = 0;
        for (int j = 0; j <= t; ++j) s += sm[j];
        int p = s - 1;
        if (sm[t] == 0) p = 1;
        pos[t] = p;
    }
}

__global__ void maskb_kernel(const int* __restrict__ mask, float* __restrict__ mb) {
    int i = blockIdx.x * blockDim.x + threadIdx.x;
    if (i < L) mb[i] = mask[i] ? 0.f : -1e9f;
}

// ---------------- embedding ----------------
__global__ __launch_bounds__(256) void embed_kernel(const int* __restrict__ ids,
                                                    const int* __restrict__ pos,
                                                    const float* __restrict__ wte,
                                                    const float* __restrict__ wpe,
                                                    float* __restrict__ h) {
    int t = blockIdx.x;
    int id = ids[t];
    int p = pos[t];
    const float* we = wte + (size_t)id * D;
    const float* wp = wpe + (size_t)p * D;
    float* hr = h + (size_t)t * D;
#pragma unroll
    for (int i = 0; i < 3; ++i) {
        int d = threadIdx.x + i * 256;
        hr[d] = we[d] + wp[d];
    }
}

// ---------------- layernorm (f32 in, f32 or bf16 out) ----------------
template <bool OUTBF>
__global__ __launch_bounds__(256) void ln_kernel(const float* __restrict__ in,
                                                 const float* __restrict__ w,
                                                 const float* __restrict__ b,
                                                 float* __restrict__ outF,
                                                 ushort* __restrict__ outB) {
    __shared__ float red[2][4];
    int row = blockIdx.x;
    const float* x = in + (size_t)row * D;
    int t = threadIdx.x;
    float v0 = x[t], v1 = x[t + 256], v2 = x[t + 512];
    float s = v0 + v1 + v2;
    float ss = v0 * v0 + v1 * v1 + v2 * v2;
#pragma unroll
    for (int o = 32; o; o >>= 1) {
        s += __shfl_xor(s, o);
        ss += __shfl_xor(ss, o);
    }
    int wave = t >> 6;
    if ((t & 63) == 0) { red[0][wave] = s; red[1][wave] = ss; }
    __syncthreads();
    s = red[0][0] + red[0][1] + red[0][2] + red[0][3];
    ss = red[1][0] + red[1][1] + red[1][2] + red[1][3];
    float mean = s * (1.f / D);
    float var = ss * (1.f / D) - mean * mean;
    float rstd = rsqrtf(var + 1e-5f);
#pragma unroll
    for (int i = 0; i < 3; ++i) {
        int d = t + i * 256;
        float vv = (i == 0) ? v0 : (i == 1) ? v1 : v2;
        float y = (vv - mean) * rstd * w[d] + b[d];
        if (OUTBF) outB[(size_t)row * D + d] = f2bf(y);
        else       outF[(size_t)row * D + d] = y;
    }
}

// ---------------- transpose-cast f32 [K][N] -> bf16 [N][K] ----------------
__global__ __launch_bounds__(256) void tcast_f32(const float* __restrict__ in,
                                                 ushort* __restrict__ out,
                                                 int K, int N) {
    __shared__ float tile[64][65];
    int k0 = blockIdx.y * 64, n0 = blockIdx.x * 64;
    int t = threadIdx.x;
    int cl = t & 63, rg = t >> 6;
#pragma unroll
    for (int i = 0; i < 16; ++i) {
        int r = rg + 4 * i;
        tile[r][cl] = in[(size_t)(k0 + r) * N + n0 + cl];
    }
    __syncthreads();
#pragma unroll
    for (int i = 0; i < 16; ++i) {
        int r = rg + 4 * i;
        out[(size_t)(n0 + r) * K + k0 + cl] = f2bf(tile[cl][r]);
    }
}

// -------- bf16 transpose: in logical [L][768] (row stride 2304) -> out [768][L]
__global__ __launch_bounds__(256) void tpose_bf16(const ushort* __restrict__ in,
                                                  ushort* __restrict__ out) {
    __shared__ int tile[64][65];
    int c0 = blockIdx.x * 64;   // column block (768 dim)
    int t0 = blockIdx.y * 64;   // row block (L dim)
    int t = threadIdx.x;
    int cl = t & 63, rg = t >> 6;
#pragma unroll
    for (int i = 0; i < 16; ++i) {
        int r = rg + 4 * i;
        tile[r][cl] = in[(size_t)(t0 + r) * QKVN + c0 + cl];
    }
    __syncthreads();
#pragma unroll
    for (int i = 0; i < 16; ++i) {
        int r = rg + 4 * i;
        out[(size_t)(c0 + r) * L + t0 + cl] = (ushort)tile[cl][r];
    }
}

// ---------------- bf16 MFMA GEMM ----------------
// C[M,N] = act(A[M,K] @ B[K,N] + bias) + resid ; B given pre-transposed [N][K]
template <int BN, int ACT, bool OUTBF>
__global__ __launch_bounds__(256) void gemm_bf16(const ushort* __restrict__ A,
                                                 const ushort* __restrict__ Bt,
                                                 const float* __restrict__ bias,
                                                 const float* __restrict__ resid,
                                                 float* __restrict__ outF,
                                                 ushort* __restrict__ outB,
                                                 int M, int N, int K) {
    constexpr int NW = (BN == 128) ? 4 : 2;
    __shared__ __align__(16) ushort As[128][40];
    __shared__ __align__(16) ushort Bs[BN][40];
    const int tid = threadIdx.x;
    const int lane = tid & 63, w = tid >> 6;
    const int wr = w >> 1, wc = w & 1;
    const int bm = blockIdx.y * 128, bn = blockIdx.x * BN;
    const int l15 = lane & 15, l4 = lane >> 4;
    const int srow = tid >> 2;
    const int skoff = (tid & 3) * 8;

    f32x4 acc[4][NW];
#pragma unroll
    for (int m = 0; m < 4; ++m)
#pragma unroll
        for (int n = 0; n < NW; ++n)
            acc[m][n] = (f32x4){0.f, 0.f, 0.f, 0.f};

    const ushort* Ag = A + (size_t)bm * K;
    const ushort* Bg = Bt + (size_t)bn * K;

    for (int k0 = 0; k0 < K; k0 += 32) {
        uint4 va0 = *(const uint4*)(Ag + (size_t)srow * K + k0 + skoff);
        uint4 va1 = *(const uint4*)(Ag + (size_t)(64 + srow) * K + k0 + skoff);
        uint4 vb0 = *(const uint4*)(Bg + (size_t)(srow & (BN - 1)) * K + k0 + skoff);
        *(uint4*)&As[srow][skoff] = va0;
        *(uint4*)&As[64 + srow][skoff] = va1;
        if (BN == 128) {
            uint4 vb1 = *(const uint4*)(Bg + (size_t)(64 + srow) * K + k0 + skoff);
            *(uint4*)&Bs[srow][skoff] = vb0;
            *(uint4*)&Bs[64 + srow][skoff] = vb1;
        } else {
            if (srow < BN) *(uint4*)&Bs[srow & (BN - 1)][skoff] = vb0;
        }
        __syncthreads();
        bf16x8 af[4], bfv[NW];
#pragma unroll
        for (int m = 0; m < 4; ++m)
            af[m] = ldfrag(&As[wr * 64 + m * 16 + l15][l4 * 4]);
#pragma unroll
        for (int n = 0; n < NW; ++n)
            bfv[n] = ldfrag(&Bs[wc * (BN / 2) + n * 16 + l15][l4 * 4]);
#pragma unroll
        for (int m = 0; m < 4; ++m)
#pragma unroll
            for (int n = 0; n < NW; ++n)
                acc[m][n] = __builtin_amdgcn_mfma_f32_16x16x32_bf16(af[m], bfv[n], acc[m][n], 0, 0, 0);
        __syncthreads();
    }

#pragma unroll
    for (int m = 0; m < 4; ++m) {
#pragma unroll
        for (int n = 0; n < NW; ++n) {
            int col = bn + wc * (BN / 2) + n * 16 + l15;
#pragma unroll
            for (int r = 0; r < 4; ++r) {
                int row = bm + wr * 64 + m * 16 + l4 * 4 + r;
                float v = acc[m][n][r];
                if (bias) v += bias[col];
                if (ACT == 1) v = gelu_tanh(v);
                if (resid) v += resid[(size_t)row * N + col];
                if (OUTBF) outB[(size_t)row * N + col] = f2bf(v);
                else       outF[(size_t)row * N + col] = v;
            }
        }
    }
}

// ---------------- MFMA flash attention ----------------
// grid (L/64, H), 256 threads = 4 waves, each wave owns 16 q-rows.
__global__ __launch_bounds__(256) void attn_kernel(const ushort* __restrict__ qkv,
                                                   const ushort* __restrict__ vT,
                                                   const float* __restrict__ maskb,
                                                   ushort* __restrict__ ctx) {
    __shared__ __align__(16) ushort Kl[32][72];
    __shared__ __align__(16) ushort Vl[64][40];
    __shared__ float Ml[32];
    const int hh = blockIdx.y;
    const int q0 = ((int)gridDim.x - 1 - (int)blockIdx.x) * 64;  // long blocks first
    const int tid = threadIdx.x;
    const int lane = tid & 63, w = tid >> 6;
    const int l15 = lane & 15, l4 = lane >> 4;
    const int qg = q0 + w * 16 + l15;

    // Q fragments (B-operand), hoisted
    bf16x8 qf[2];
#pragma unroll
    for (int ks = 0; ks < 2; ++ks)
        qf[ks] = ldfrag(qkv + (size_t)qg * QKVN + hh * 64 + ks * 32 + l4 * 4);

    f32x4 o[4];
#pragma unroll
    for (int i = 0; i < 4; ++i) o[i] = (f32x4){0.f, 0.f, 0.f, 0.f};
    float mrun = -1e30f, lrun = 0.f;

    const int skey = tid >> 3, sko = (tid & 7) * 8;
    const int sdh = tid >> 2, skq = (tid & 3) * 8;
    const int nt = q0 / 32 + 2;

    for (int it = 0; it < nt; ++it) {
        const int kv0 = it * 32;
        // stage K (32x64), V^T (64x32), mask
        uint4 kv = *(const uint4*)(qkv + (size_t)(kv0 + skey) * QKVN + D + hh * 64 + sko);
        uint4 vv = *(const uint4*)(vT + (size_t)(hh * 64 + sdh) * L + kv0 + skq);
        *(uint4*)&Kl[skey][sko] = kv;
        *(uint4*)&Vl[sdh][skq] = vv;
        if (tid < 32) Ml[tid] = maskb[kv0 + tid];
        __syncthreads();

        // S^T = K @ Q^T  (rows = keys, cols = q)
        f32x4 st[2];
        st[0] = (f32x4){0.f, 0.f, 0.f, 0.f};
        st[1] = (f32x4){0.f, 0.f, 0.f, 0.f};
#pragma unroll
        for (int m = 0; m < 2; ++m)
#pragma unroll
            for (int ks = 0; ks < 2; ++ks) {
                bf16x8 kf = ldfrag(&Kl[m * 16 + l15][ks * 32 + l4 * 4]);
                st[m] = __builtin_amdgcn_mfma_f32_16x16x32_bf16(kf, qf[ks], st[m], 0, 0, 0);
            }

        // online softmax over key dim (4 lane-groups x 8 in-lane values)
        float p[2][4];
        float tmax = -1e30f;
#pragma unroll
        for (int m = 0; m < 2; ++m)
#pragma unroll
            for (int r = 0; r < 4; ++r) {
                int kl = m * 16 + l4 * 4 + r;
                float s = st[m][r] + Ml[kl];
                if (kv0 + kl > qg) s = -1e30f;
                p[m][r] = s;
                tmax = fmaxf(tmax, s);
            }
        tmax = fmaxf(tmax, __shfl_xor(tmax, 16));
        tmax = fmaxf(tmax, __shfl_xor(tmax, 32));
        float mnew = fmaxf(mrun, tmax);
        float scale = __expf(mrun - mnew);
        float ts = 0.f;
#pragma unroll
        for (int m = 0; m < 2; ++m)
#pragma unroll
            for (int r = 0; r < 4; ++r) {
                float e = __expf(p[m][r] - mnew);
                p[m][r] = e;
                ts += e;
            }
        ts += __shfl_xor(ts, 16);
        ts += __shfl_xor(ts, 32);
        lrun = lrun * scale + ts;
        mrun = mnew;

        // P^T fragment is in-register: elems 0-3 = keys m=0, 4-7 = keys m=1
        bf16x8 pf;
#pragma unroll
        for (int r = 0; r < 4; ++r) {
            pf[r]     = (short)f2bf(p[0][r]);
            pf[4 + r] = (short)f2bf(p[1][r]);
        }
#pragma unroll
        for (int i = 0; i < 4; ++i) {
            o[i][0] *= scale; o[i][1] *= scale; o[i][2] *= scale; o[i][3] *= scale;
        }
#pragma unroll
        for (int dhb = 0; dhb < 4; ++dhb) {
            bf16x8 vf = ldfrag(&Vl[dhb * 16 + l15][l4 * 4]);
            o[dhb] = __builtin_amdgcn_mfma_f32_16x16x32_bf16(vf, pf, o[dhb], 0, 0, 0);
        }
        __syncthreads();
    }

    float rinv = 1.0f / lrun;
#pragma unroll
    for (int dhb = 0; dhb < 4; ++dhb) {
        ushort4 pk;
        pk.x = f2bf(o[dhb][0] * rinv);
        pk.y = f2bf(o[dhb][1] * rinv);
        pk.z = f2bf(o[dhb][2] * rinv);
        pk.w = f2bf(o[dhb][3] * rinv);
        *(ushort4*)(ctx + (size_t)qg * D + hh * 64 + dhb * 16 + l4 * 4) = pk;
    }
}

extern "C" void kernel_launch(void* const* d_in, const int* in_sizes, int n_in,
                              void* d_out, int out_size, void* d_ws, size_t ws_size,
                              hipStream_t stream) {
    const int* ids = (const int*)d_in[0];
    const int* amask = (const int*)d_in[1];
    const float* wte = (const float*)d_in[2];
    const float* wpe = (const float*)d_in[3];
    const float* lnf_w = (const float*)d_in[4];
    const float* lnf_b = (const float*)d_in[5];
    const float* ln1_w = (const float*)d_in[6];
    const float* ln1_b = (const float*)d_in[7];
    const float* qw = (const float*)d_in[8];
    const float* kw = (const float*)d_in[9];
    const float* vw = (const float*)d_in[10];
    const float* ow = (const float*)d_in[11];
    const float* ob = (const float*)d_in[12];
    const float* ln2_w = (const float*)d_in[13];
    const float* ln2_b = (const float*)d_in[14];
    const float* fcw = (const float*)d_in[15];
    const float* fcb = (const float*)d_in[16];
    const float* pw = (const float*)d_in[17];
    const float* pb = (const float*)d_in[18];

    char* p = (char*)d_ws;
    auto take = [&](size_t bytes) -> char* {
        char* r = p;
        p += (bytes + 4095) & ~(size_t)4095;
        return r;
    };
    ushort* wqkvT = (ushort*)take((size_t)NL * QKVN * D * 2);
    ushort* woT   = (ushort*)take((size_t)NL * D * D * 2);
    ushort* fcwT  = (ushort*)take((size_t)NL * F * D * 2);
    ushort* pwT   = (ushort*)take((size_t)NL * D * F * 2);
    float*  h     = (float*)take((size_t)L * D * 4);
    ushort* xb    = (ushort*)take((size_t)L * D * 2);
    ushort* qkvb  = (ushort*)take((size_t)L * QKVN * 2);
    ushort* vTb   = (ushort*)take((size_t)D * L * 2);
    ushort* ctxb  = (ushort*)take((size_t)L * D * 2);
    ushort* f1b   = (ushort*)take((size_t)L * F * 2);
    float*  mb    = (float*)take(L * 4);
    int*    pos   = (int*)take(L * 4);

    pos_kernel<<<8, 256, 0, stream>>>(amask, pos);
    maskb_kernel<<<8, 256, 0, stream>>>(amask, mb);
    embed_kernel<<<L, 256, 0, stream>>>(ids, pos, wte, wpe, h);

    // weight transpose-casts (once per call)
    for (int l = 0; l < NL; ++l) {
        tcast_f32<<<dim3(12, 12), 256, 0, stream>>>(qw + (size_t)l * D * D,
                                                    wqkvT + (size_t)l * QKVN * D, D, D);
        tcast_f32<<<dim3(12, 12), 256, 0, stream>>>(kw + (size_t)l * D * D,
                                                    wqkvT + (size_t)l * QKVN * D + (size_t)D * D, D, D);
        tcast_f32<<<dim3(12, 12), 256, 0, stream>>>(vw + (size_t)l * D * D,
                                                    wqkvT + (size_t)l * QKVN * D + (size_t)2 * D * D, D, D);
        tcast_f32<<<dim3(12, 12), 256, 0, stream>>>(ow + (size_t)l * D * D,
                                                    woT + (size_t)l * D * D, D, D);
        tcast_f32<<<dim3(48, 12), 256, 0, stream>>>(fcw + (size_t)l * D * F,
                                                    fcwT + (size_t)l * F * D, D, F);
        tcast_f32<<<dim3(12, 48), 256, 0, stream>>>(pw + (size_t)l * F * D,
                                                    pwT + (size_t)l * D * F, F, D);
    }

    for (int l = 0; l < NL; ++l) {
        ln_kernel<true><<<L, 256, 0, stream>>>(h, ln1_w + l * D, ln1_b + l * D, nullptr, xb);
        gemm_bf16<128, 0, true><<<dim3(QKVN / 128, L / 128), 256, 0, stream>>>(
            xb, wqkvT + (size_t)l * QKVN * D, nullptr, nullptr, nullptr, qkvb, L, QKVN, D);
        tpose_bf16<<<dim3(12, 32), 256, 0, stream>>>(qkvb + 2 * D, vTb);
        attn_kernel<<<dim3(L / 64, H), 256, 0, stream>>>(qkvb, vTb, mb, ctxb);
        gemm_bf16<64, 0, false><<<dim3(D / 64, L / 128), 256, 0, stream>>>(
            ctxb, woT + (size_t)l * D * D, ob + l * D, h, h, nullptr, L, D, D);
        ln_kernel<true><<<L, 256, 0, stream>>>(h, ln2_w + l * D, ln2_b + l * D, nullptr, xb);
        gemm_bf16<128, 1, true><<<dim3(F / 128, L / 128), 256, 0, stream>>>(
            xb, fcwT + (size_t)l * F * D, fcb + l * F, nullptr, nullptr, f1b, L, F, D);
        gemm_bf16<64, 0, false><<<dim3(D / 64, L / 128), 256, 0, stream>>>(
            f1b, pwT + (size_t)l * D * F, pb + l * D, h, h, nullptr, L, D, F);
    }
    ln_kernel<false><<<L, 256, 0, stream>>>(h, lnf_w, lnf_b, (float*)d_out, nullptr);
}

// Round 3
// 2670.532 us; speedup vs baseline: 12.0497x; 1.4099x over previous
//
#include <hip/hip_runtime.h>
#include <hip/hip_bf16.h>
#include <math.h>
#include <stdint.h>

#define L 2048
#define D 768
#define H 12
#define DH 64
#define F 3072
#define NL 12
#define QKVN 2304

typedef __attribute__((ext_vector_type(8))) short bf16x8;
typedef __attribute__((ext_vector_type(4))) float f32x4;

__device__ __forceinline__ ushort f2bf(float x) {
    union { float f; uint32_t u; } c; c.f = x;
    uint32_t r = c.u + 0x7FFFu + ((c.u >> 16) & 1u);
    return (ushort)(r >> 16);
}

// load one MFMA A/B fragment (16x16x32 bf16) from row-major [*][stride] tile:
// elems 0-3 at p, 4-7 at p+16  (used by attention kernel only)
__device__ __forceinline__ bf16x8 ldfrag(const ushort* p) {
    ushort4 lo = *(const ushort4*)(p);
    ushort4 hi = *(const ushort4*)(p + 16);
    bf16x8 f;
    f[0] = (short)lo.x; f[1] = (short)lo.y; f[2] = (short)lo.z; f[3] = (short)lo.w;
    f[4] = (short)hi.x; f[5] = (short)hi.y; f[6] = (short)hi.z; f[7] = (short)hi.w;
    return f;
}

__device__ __forceinline__ float gelu_tanh(float x) {
    float c = 0.7978845608028654f;
    float inner = c * (x + 0.044715f * x * x * x);
    return 0.5f * x * (1.0f + tanhf(inner));
}

// ---------------- position cumsum ----------------
__global__ void pos_kernel(const int* __restrict__ mask, int* __restrict__ pos) {
    __shared__ int sm[L];
    for (int i = threadIdx.x; i < L; i += blockDim.x) sm[i] = mask[i];
    __syncthreads();
    int t = blockIdx.x * blockDim.x + threadIdx.x;
    if (t < L) {
        int s = 0;
        for (int j = 0; j <= t; ++j) s += sm[j];
        int p = s - 1;
        if (sm[t] == 0) p = 1;
        pos[t] = p;
    }
}

__global__ void maskb_kernel(const int* __restrict__ mask, float* __restrict__ mb) {
    int i = blockIdx.x * blockDim.x + threadIdx.x;
    if (i < L) mb[i] = mask[i] ? 0.f : -1e9f;
}

// ---------------- embedding ----------------
__global__ __launch_bounds__(256) void embed_kernel(const int* __restrict__ ids,
                                                    const int* __restrict__ pos,
                                                    const float* __restrict__ wte,
                                                    const float* __restrict__ wpe,
                                                    float* __restrict__ h) {
    int t = blockIdx.x;
    int id = ids[t];
    int p = pos[t];
    const float* we = wte + (size_t)id * D;
    const float* wp = wpe + (size_t)p * D;
    float* hr = h + (size_t)t * D;
#pragma unroll
    for (int i = 0; i < 3; ++i) {
        int d = threadIdx.x + i * 256;
        hr[d] = we[d] + wp[d];
    }
}

// ---------------- layernorm (f32 in, bf16 out) ----------------
template <bool OUTBF>
__global__ __launch_bounds__(256) void ln_kernel(const float* __restrict__ in,
                                                 const float* __restrict__ w,
                                                 const float* __restrict__ b,
                                                 float* __restrict__ outF,
                                                 ushort* __restrict__ outB) {
    __shared__ float red[2][4];
    int row = blockIdx.x;
    const float* x = in + (size_t)row * D;
    int t = threadIdx.x;
    float v0 = x[t], v1 = x[t + 256], v2 = x[t + 512];
    float s = v0 + v1 + v2;
    float ss = v0 * v0 + v1 * v1 + v2 * v2;
#pragma unroll
    for (int o = 32; o; o >>= 1) {
        s += __shfl_xor(s, o);
        ss += __shfl_xor(ss, o);
    }
    int wave = t >> 6;
    if ((t & 63) == 0) { red[0][wave] = s; red[1][wave] = ss; }
    __syncthreads();
    s = red[0][0] + red[0][1] + red[0][2] + red[0][3];
    ss = red[1][0] + red[1][1] + red[1][2] + red[1][3];
    float mean = s * (1.f / D);
    float var = ss * (1.f / D) - mean * mean;
    float rstd = rsqrtf(var + 1e-5f);
#pragma unroll
    for (int i = 0; i < 3; ++i) {
        int d = t + i * 256;
        float vv = (i == 0) ? v0 : (i == 1) ? v1 : v2;
        float y = (vv - mean) * rstd * w[d] + b[d];
        if (OUTBF) outB[(size_t)row * D + d] = f2bf(y);
        else       outF[(size_t)row * D + d] = y;
    }
}

// ---- fused split-K reduce + bias + residual(h) + LayerNorm -> bf16 (or f32) ----
template <int S, bool OUTBF>
__global__ __launch_bounds__(256) void redln_kernel(const float* __restrict__ part,
                                                    const float* __restrict__ bias,
                                                    float* __restrict__ h,
                                                    const float* __restrict__ lnw,
                                                    const float* __restrict__ lnb,
                                                    ushort* __restrict__ outB,
                                                    float* __restrict__ outF) {
    __shared__ float red[2][4];
    int row = blockIdx.x;
    int t = threadIdx.x;
    float v[3];
    float s = 0.f, ss = 0.f;
#pragma unroll
    for (int i = 0; i < 3; ++i) {
        int d = t + i * 256;
        float x = h[(size_t)row * D + d] + bias[d];
#pragma unroll
        for (int sp = 0; sp < S; ++sp)
            x += part[((size_t)sp * L + row) * D + d];
        v[i] = x;
        h[(size_t)row * D + d] = x;
        s += x;
        ss += x * x;
    }
#pragma unroll
    for (int o = 32; o; o >>= 1) {
        s += __shfl_xor(s, o);
        ss += __shfl_xor(ss, o);
    }
    int wave = t >> 6;
    if ((t & 63) == 0) { red[0][wave] = s; red[1][wave] = ss; }
    __syncthreads();
    s = red[0][0] + red[0][1] + red[0][2] + red[0][3];
    ss = red[1][0] + red[1][1] + red[1][2] + red[1][3];
    float mean = s * (1.f / D);
    float var = ss * (1.f / D) - mean * mean;
    float rstd = rsqrtf(var + 1e-5f);
#pragma unroll
    for (int i = 0; i < 3; ++i) {
        int d = t + i * 256;
        float y = (v[i] - mean) * rstd * lnw[d] + lnb[d];
        if (OUTBF) outB[(size_t)row * D + d] = f2bf(y);
        else       outF[(size_t)row * D + d] = y;
    }
}

// ---------------- transpose-cast f32 [K][N] -> bf16 [N][K], z = layer ----------------
__global__ __launch_bounds__(256) void tcast_f32(const float* __restrict__ in,
                                                 ushort* __restrict__ out,
                                                 int K, int N,
                                                 size_t inStride, size_t outStride) {
    in += blockIdx.z * inStride;
    out += blockIdx.z * outStride;
    __shared__ float tile[64][65];
    int k0 = blockIdx.y * 64, n0 = blockIdx.x * 64;
    int t = threadIdx.x;
    int cl = t & 63, rg = t >> 6;
#pragma unroll
    for (int i = 0; i < 16; ++i) {
        int r = rg + 4 * i;
        tile[r][cl] = in[(size_t)(k0 + r) * N + n0 + cl];
    }
    __syncthreads();
#pragma unroll
    for (int i = 0; i < 16; ++i) {
        int r = rg + 4 * i;
        out[(size_t)(n0 + r) * K + k0 + cl] = f2bf(tile[cl][r]);
    }
}

// -------- bf16 transpose: in logical [L][768] (row stride 2304) -> out [768][L]
__global__ __launch_bounds__(256) void tpose_bf16(const ushort* __restrict__ in,
                                                  ushort* __restrict__ out) {
    __shared__ int tile[64][65];
    int c0 = blockIdx.x * 64;
    int t0 = blockIdx.y * 64;
    int t = threadIdx.x;
    int cl = t & 63, rg = t >> 6;
#pragma unroll
    for (int i = 0; i < 16; ++i) {
        int r = rg + 4 * i;
        tile[r][cl] = in[(size_t)(t0 + r) * QKVN + c0 + cl];
    }
    __syncthreads();
#pragma unroll
    for (int i = 0; i < 16; ++i) {
        int r = rg + 4 * i;
        out[(size_t)(c0 + r) * L + t0 + cl] = (ushort)tile[cl][r];
    }
}

// ---------------- bf16 MFMA GEMM, 128x128 tile, BK=32 ----------------
// LDS layout: per row 64B holding the 32 k-values permuted so that one MFMA
// fragment = one contiguous 16B b128 read; rows XOR-swizzled by (row&3)<<4.
// SPLITK>1: blockIdx.z = split s over K/SPLITK chunk, writes f32 partial.
template <int ACT, bool OUTBF, int SPLITK>
__global__ __launch_bounds__(256) void gemm_bf16(const ushort* __restrict__ A,
                                                 const ushort* __restrict__ Bt,
                                                 const float* __restrict__ bias,
                                                 const float* __restrict__ resid,
                                                 float* __restrict__ outF,
                                                 ushort* __restrict__ outB,
                                                 float* __restrict__ pout,
                                                 int M, int N, int K) {
    __shared__ __align__(16) char lds[16384];
    char* Ab = lds;
    char* Bb = lds + 8192;
    const int tid = threadIdx.x;
    const int lane = tid & 63, w = tid >> 6;
    const int wr = w >> 1, wc = w & 1;
    const int bm = blockIdx.y * 128, bn = blockIdx.x * 128;
    const int l15 = lane & 15, l4 = lane >> 4;
    const int srow = tid >> 2, c = tid & 3;
    const int blo = (c & 1) * 32 + (c >> 1) * 8;
    const int kLen = K / SPLITK;
    const int kStart = (SPLITK > 1) ? blockIdx.z * kLen : 0;

    // staging LDS byte offsets (same for A and B tiles)
    const int sxor = (srow & 3) << 4;
    const int wo0 = srow * 64 + (blo ^ sxor);
    const int wo1 = srow * 64 + ((blo + 16) ^ sxor);
    // fragment read base offsets
    const int rxor = (l4 * 16) ^ ((l15 & 3) << 4);
    const int aBase = (wr * 64 + l15) * 64 + rxor;
    const int bBase = (wc * 64 + l15) * 64 + rxor;

    f32x4 acc[4][4];
#pragma unroll
    for (int m = 0; m < 4; ++m)
#pragma unroll
        for (int n = 0; n < 4; ++n)
            acc[m][n] = (f32x4){0.f, 0.f, 0.f, 0.f};

    const ushort* Ag = A + (size_t)(bm + srow) * K + kStart + c * 8;
    const ushort* Ag2 = Ag + (size_t)64 * K;
    const ushort* Bg = Bt + (size_t)(bn + srow) * K + kStart + c * 8;
    const ushort* Bg2 = Bg + (size_t)64 * K;

    for (int k0 = 0; k0 < kLen; k0 += 32) {
        uint4 a0 = *(const uint4*)(Ag + k0);
        uint4 a1 = *(const uint4*)(Ag2 + k0);
        uint4 b0 = *(const uint4*)(Bg + k0);
        uint4 b1 = *(const uint4*)(Bg2 + k0);
        uint2 t0, t1;
        t0.x = a0.x; t0.y = a0.y; t1.x = a0.z; t1.y = a0.w;
        *(uint2*)(Ab + wo0) = t0;
        *(uint2*)(Ab + wo1) = t1;
        t0.x = a1.x; t0.y = a1.y; t1.x = a1.z; t1.y = a1.w;
        *(uint2*)(Ab + wo0 + 4096) = t0;
        *(uint2*)(Ab + wo1 + 4096) = t1;
        t0.x = b0.x; t0.y = b0.y; t1.x = b0.z; t1.y = b0.w;
        *(uint2*)(Bb + wo0) = t0;
        *(uint2*)(Bb + wo1) = t1;
        t0.x = b1.x; t0.y = b1.y; t1.x = b1.z; t1.y = b1.w;
        *(uint2*)(Bb + wo0 + 4096) = t0;
        *(uint2*)(Bb + wo1 + 4096) = t1;
        __syncthreads();
        bf16x8 af[4], bfv[4];
#pragma unroll
        for (int m = 0; m < 4; ++m)
            af[m] = *(const bf16x8*)(Ab + aBase + m * 1024);
#pragma unroll
        for (int n = 0; n < 4; ++n)
            bfv[n] = *(const bf16x8*)(Bb + bBase + n * 1024);
#pragma unroll
        for (int m = 0; m < 4; ++m)
#pragma unroll
            for (int n = 0; n < 4; ++n)
                acc[m][n] = __builtin_amdgcn_mfma_f32_16x16x32_bf16(af[m], bfv[n], acc[m][n], 0, 0, 0);
        __syncthreads();
    }

    if (SPLITK > 1) {
        const size_t sb = (size_t)blockIdx.z * M;
#pragma unroll
        for (int m = 0; m < 4; ++m)
#pragma unroll
            for (int n = 0; n < 4; ++n) {
                int col = bn + wc * 64 + n * 16 + l15;
#pragma unroll
                for (int r = 0; r < 4; ++r) {
                    int row = bm + wr * 64 + m * 16 + l4 * 4 + r;
                    pout[(sb + row) * N + col] = acc[m][n][r];
                }
            }
    } else {
#pragma unroll
        for (int m = 0; m < 4; ++m)
#pragma unroll
            for (int n = 0; n < 4; ++n) {
                int col = bn + wc * 64 + n * 16 + l15;
#pragma unroll
                for (int r = 0; r < 4; ++r) {
                    int row = bm + wr * 64 + m * 16 + l4 * 4 + r;
                    float v = acc[m][n][r];
                    if (bias) v += bias[col];
                    if (ACT == 1) v = gelu_tanh(v);
                    if (resid) v += resid[(size_t)row * N + col];
                    if (OUTBF) outB[(size_t)row * N + col] = f2bf(v);
                    else       outF[(size_t)row * N + col] = v;
                }
            }
    }
}

// ---------------- MFMA flash attention ----------------
__global__ __launch_bounds__(256) void attn_kernel(const ushort* __restrict__ qkv,
                                                   const ushort* __restrict__ vT,
                                                   const float* __restrict__ maskb,
                                                   ushort* __restrict__ ctx) {
    __shared__ __align__(16) ushort Kl[32][72];
    __shared__ __align__(16) ushort Vl[64][40];
    __shared__ float Ml[32];
    const int hh = blockIdx.y;
    const int q0 = ((int)gridDim.x - 1 - (int)blockIdx.x) * 64;
    const int tid = threadIdx.x;
    const int lane = tid & 63, w = tid >> 6;
    const int l15 = lane & 15, l4 = lane >> 4;
    const int qg = q0 + w * 16 + l15;

    bf16x8 qf[2];
#pragma unroll
    for (int ks = 0; ks < 2; ++ks)
        qf[ks] = ldfrag(qkv + (size_t)qg * QKVN + hh * 64 + ks * 32 + l4 * 4);

    f32x4 o[4];
#pragma unroll
    for (int i = 0; i < 4; ++i) o[i] = (f32x4){0.f, 0.f, 0.f, 0.f};
    float mrun = -1e30f, lrun = 0.f;

    const int skey = tid >> 3, sko = (tid & 7) * 8;
    const int sdh = tid >> 2, skq = (tid & 3) * 8;
    const int nt = q0 / 32 + 2;

    for (int it = 0; it < nt; ++it) {
        const int kv0 = it * 32;
        uint4 kv = *(const uint4*)(qkv + (size_t)(kv0 + skey) * QKVN + D + hh * 64 + sko);
        uint4 vv = *(const uint4*)(vT + (size_t)(hh * 64 + sdh) * L + kv0 + skq);
        *(uint4*)&Kl[skey][sko] = kv;
        *(uint4*)&Vl[sdh][skq] = vv;
        if (tid < 32) Ml[tid] = maskb[kv0 + tid];
        __syncthreads();

        f32x4 st[2];
        st[0] = (f32x4){0.f, 0.f, 0.f, 0.f};
        st[1] = (f32x4){0.f, 0.f, 0.f, 0.f};
#pragma unroll
        for (int m = 0; m < 2; ++m)
#pragma unroll
            for (int ks = 0; ks < 2; ++ks) {
                bf16x8 kf = ldfrag(&Kl[m * 16 + l15][ks * 32 + l4 * 4]);
                st[m] = __builtin_amdgcn_mfma_f32_16x16x32_bf16(kf, qf[ks], st[m], 0, 0, 0);
            }

        float p[2][4];
        float tmax = -1e30f;
#pragma unroll
        for (int m = 0; m < 2; ++m)
#pragma unroll
            for (int r = 0; r < 4; ++r) {
                int kl = m * 16 + l4 * 4 + r;
                float s = st[m][r] + Ml[kl];
                if (kv0 + kl > qg) s = -1e30f;
                p[m][r] = s;
                tmax = fmaxf(tmax, s);
            }
        tmax = fmaxf(tmax, __shfl_xor(tmax, 16));
        tmax = fmaxf(tmax, __shfl_xor(tmax, 32));
        float mnew = fmaxf(mrun, tmax);
        float scale = __expf(mrun - mnew);
        float ts = 0.f;
#pragma unroll
        for (int m = 0; m < 2; ++m)
#pragma unroll
            for (int r = 0; r < 4; ++r) {
                float e = __expf(p[m][r] - mnew);
                p[m][r] = e;
                ts += e;
            }
        ts += __shfl_xor(ts, 16);
        ts += __shfl_xor(ts, 32);
        lrun = lrun * scale + ts;
        mrun = mnew;

        bf16x8 pf;
#pragma unroll
        for (int r = 0; r < 4; ++r) {
            pf[r]     = (short)f2bf(p[0][r]);
            pf[4 + r] = (short)f2bf(p[1][r]);
        }
#pragma unroll
        for (int i = 0; i < 4; ++i) {
            o[i][0] *= scale; o[i][1] *= scale; o[i][2] *= scale; o[i][3] *= scale;
        }
#pragma unroll
        for (int dhb = 0; dhb < 4; ++dhb) {
            bf16x8 vf = ldfrag(&Vl[dhb * 16 + l15][l4 * 4]);
            o[dhb] = __builtin_amdgcn_mfma_f32_16x16x32_bf16(vf, pf, o[dhb], 0, 0, 0);
        }
        __syncthreads();
    }

    float rinv = 1.0f / lrun;
#pragma unroll
    for (int dhb = 0; dhb < 4; ++dhb) {
        ushort4 pk;
        pk.x = f2bf(o[dhb][0] * rinv);
        pk.y = f2bf(o[dhb][1] * rinv);
        pk.z = f2bf(o[dhb][2] * rinv);
        pk.w = f2bf(o[dhb][3] * rinv);
        *(ushort4*)(ctx + (size_t)qg * D + hh * 64 + dhb * 16 + l4 * 4) = pk;
    }
}

extern "C" void kernel_launch(void* const* d_in, const int* in_sizes, int n_in,
                              void* d_out, int out_size, void* d_ws, size_t ws_size,
                              hipStream_t stream) {
    const int* ids = (const int*)d_in[0];
    const int* amask = (const int*)d_in[1];
    const float* wte = (const float*)d_in[2];
    const float* wpe = (const float*)d_in[3];
    const float* lnf_w = (const float*)d_in[4];
    const float* lnf_b = (const float*)d_in[5];
    const float* ln1_w = (const float*)d_in[6];
    const float* ln1_b = (const float*)d_in[7];
    const float* qw = (const float*)d_in[8];
    const float* kw = (const float*)d_in[9];
    const float* vw = (const float*)d_in[10];
    const float* ow = (const float*)d_in[11];
    const float* ob = (const float*)d_in[12];
    const float* ln2_w = (const float*)d_in[13];
    const float* ln2_b = (const float*)d_in[14];
    const float* fcw = (const float*)d_in[15];
    const float* fcb = (const float*)d_in[16];
    const float* pw = (const float*)d_in[17];
    const float* pb = (const float*)d_in[18];

    char* p = (char*)d_ws;
    auto take = [&](size_t bytes) -> char* {
        char* r = p;
        p += (bytes + 4095) & ~(size_t)4095;
        return r;
    };
    ushort* wqkvT = (ushort*)take((size_t)NL * QKVN * D * 2);
    ushort* woT   = (ushort*)take((size_t)NL * D * D * 2);
    ushort* fcwT  = (ushort*)take((size_t)NL * F * D * 2);
    ushort* pwT   = (ushort*)take((size_t)NL * D * F * 2);
    float*  h     = (float*)take((size_t)L * D * 4);
    ushort* xb    = (ushort*)take((size_t)L * D * 2);
    ushort* qkvb  = (ushort*)take((size_t)L * QKVN * 2);
    ushort* vTb   = (ushort*)take((size_t)D * L * 2);
    ushort* ctxb  = (ushort*)take((size_t)L * D * 2);
    ushort* f1b   = (ushort*)take((size_t)L * F * 2);
    float*  pk    = (float*)take((size_t)4 * L * D * 4);   // split-K partials
    float*  mb    = (float*)take(L * 4);
    int*    pos   = (int*)take(L * 4);

    pos_kernel<<<8, 256, 0, stream>>>(amask, pos);
    maskb_kernel<<<8, 256, 0, stream>>>(amask, mb);
    embed_kernel<<<L, 256, 0, stream>>>(ids, pos, wte, wpe, h);

    // weight transpose-casts, z = layer
    tcast_f32<<<dim3(12, 12, NL), 256, 0, stream>>>(qw, wqkvT, D, D,
                                                    (size_t)D * D, (size_t)QKVN * D);
    tcast_f32<<<dim3(12, 12, NL), 256, 0, stream>>>(kw, wqkvT + (size_t)D * D, D, D,
                                                    (size_t)D * D, (size_t)QKVN * D);
    tcast_f32<<<dim3(12, 12, NL), 256, 0, stream>>>(vw, wqkvT + (size_t)2 * D * D, D, D,
                                                    (size_t)D * D, (size_t)QKVN * D);
    tcast_f32<<<dim3(12, 12, NL), 256, 0, stream>>>(ow, woT, D, D,
                                                    (size_t)D * D, (size_t)D * D);
    tcast_f32<<<dim3(48, 12, NL), 256, 0, stream>>>(fcw, fcwT, D, F,
                                                    (size_t)D * F, (size_t)F * D);
    tcast_f32<<<dim3(12, 48, NL), 256, 0, stream>>>(pw, pwT, F, D,
                                                    (size_t)F * D, (size_t)D * F);

    // layer 0 ln1
    ln_kernel<true><<<L, 256, 0, stream>>>(h, ln1_w, ln1_b, nullptr, xb);

    for (int l = 0; l < NL; ++l) {
        gemm_bf16<0, true, 1><<<dim3(QKVN / 128, L / 128), 256, 0, stream>>>(
            xb, wqkvT + (size_t)l * QKVN * D, nullptr, nullptr, nullptr, qkvb, nullptr,
            L, QKVN, D);
        tpose_bf16<<<dim3(12, 32), 256, 0, stream>>>(qkvb + 2 * D, vTb);
        attn_kernel<<<dim3(L / 64, H), 256, 0, stream>>>(qkvb, vTb, mb, ctxb);
        gemm_bf16<0, true, 4><<<dim3(D / 128, L / 128, 4), 256, 0, stream>>>(
            ctxb, woT + (size_t)l * D * D, nullptr, nullptr, nullptr, nullptr, pk,
            L, D, D);
        redln_kernel<4, true><<<L, 256, 0, stream>>>(
            pk, ob + l * D, h, ln2_w + l * D, ln2_b + l * D, xb, nullptr);
        gemm_bf16<1, true, 1><<<dim3(F / 128, L / 128), 256, 0, stream>>>(
            xb, fcwT + (size_t)l * F * D, fcb + l * F, nullptr, nullptr, f1b, nullptr,
            L, F, D);
        gemm_bf16<0, true, 4><<<dim3(D / 128, L / 128, 4), 256, 0, stream>>>(
            f1b, pwT + (size_t)l * D * F, nullptr, nullptr, nullptr, nullptr, pk,
            L, D, F);
        if (l < NL - 1) {
            redln_kernel<4, true><<<L, 256, 0, stream>>>(
                pk, pb + l * D, h, ln1_w + (l + 1) * D, ln1_b + (l + 1) * D, xb, nullptr);
        } else {
            redln_kernel<4, false><<<L, 256, 0, stream>>>(
                pk, pb + l * D, h, lnf_w, lnf_b, nullptr, (float*)d_out);
        }
    }
}

// Round 4
// 2199.307 us; speedup vs baseline: 14.6315x; 1.2143x over previous
//
#include <hip/hip_runtime.h>
#include <hip/hip_bf16.h>
#include <math.h>
#include <stdint.h>

#define L 2048
#define D 768
#define H 12
#define DH 64
#define F 3072
#define NL 12
#define QKVN 2304

typedef __attribute__((ext_vector_type(8))) short bf16x8;
typedef __attribute__((ext_vector_type(4))) float f32x4;

__device__ __forceinline__ ushort f2bf(float x) {
    union { float f; uint32_t u; } c; c.f = x;
    uint32_t r = c.u + 0x7FFFu + ((c.u >> 16) & 1u);
    return (ushort)(r >> 16);
}

__device__ __forceinline__ bf16x8 ldfrag(const ushort* p) {
    ushort4 lo = *(const ushort4*)(p);
    ushort4 hi = *(const ushort4*)(p + 16);
    bf16x8 f;
    f[0] = (short)lo.x; f[1] = (short)lo.y; f[2] = (short)lo.z; f[3] = (short)lo.w;
    f[4] = (short)hi.x; f[5] = (short)hi.y; f[6] = (short)hi.z; f[7] = (short)hi.w;
    return f;
}

__device__ __forceinline__ float gelu_tanh(float x) {
    float c = 0.7978845608028654f;
    float inner = c * (x + 0.044715f * x * x * x);
    return 0.5f * x * (1.0f + tanhf(inner));
}

// ---------------- position cumsum ----------------
__global__ void pos_kernel(const int* __restrict__ mask, int* __restrict__ pos) {
    __shared__ int sm[L];
    for (int i = threadIdx.x; i < L; i += blockDim.x) sm[i] = mask[i];
    __syncthreads();
    int t = blockIdx.x * blockDim.x + threadIdx.x;
    if (t < L) {
        int s = 0;
        for (int j = 0; j <= t; ++j) s += sm[j];
        int p = s - 1;
        if (sm[t] == 0) p = 1;
        pos[t] = p;
    }
}

__global__ void maskb_kernel(const int* __restrict__ mask, float* __restrict__ mb) {
    int i = blockIdx.x * blockDim.x + threadIdx.x;
    if (i < L) mb[i] = mask[i] ? 0.f : -1e9f;
}

// ---------------- embedding ----------------
__global__ __launch_bounds__(256) void embed_kernel(const int* __restrict__ ids,
                                                    const int* __restrict__ pos,
                                                    const float* __restrict__ wte,
                                                    const float* __restrict__ wpe,
                                                    float* __restrict__ h) {
    int t = blockIdx.x;
    int id = ids[t];
    int p = pos[t];
    const float* we = wte + (size_t)id * D;
    const float* wp = wpe + (size_t)p * D;
    float* hr = h + (size_t)t * D;
#pragma unroll
    for (int i = 0; i < 3; ++i) {
        int d = threadIdx.x + i * 256;
        hr[d] = we[d] + wp[d];
    }
}

// ---------------- layernorm (f32 in, bf16 out) ----------------
template <bool OUTBF>
__global__ __launch_bounds__(256) void ln_kernel(const float* __restrict__ in,
                                                 const float* __restrict__ w,
                                                 const float* __restrict__ b,
                                                 float* __restrict__ outF,
                                                 ushort* __restrict__ outB) {
    __shared__ float red[2][4];
    int row = blockIdx.x;
    const float* x = in + (size_t)row * D;
    int t = threadIdx.x;
    float v0 = x[t], v1 = x[t + 256], v2 = x[t + 512];
    float s = v0 + v1 + v2;
    float ss = v0 * v0 + v1 * v1 + v2 * v2;
#pragma unroll
    for (int o = 32; o; o >>= 1) {
        s += __shfl_xor(s, o);
        ss += __shfl_xor(ss, o);
    }
    int wave = t >> 6;
    if ((t & 63) == 0) { red[0][wave] = s; red[1][wave] = ss; }
    __syncthreads();
    s = red[0][0] + red[0][1] + red[0][2] + red[0][3];
    ss = red[1][0] + red[1][1] + red[1][2] + red[1][3];
    float mean = s * (1.f / D);
    float var = ss * (1.f / D) - mean * mean;
    float rstd = rsqrtf(var + 1e-5f);
#pragma unroll
    for (int i = 0; i < 3; ++i) {
        int d = t + i * 256;
        float vv = (i == 0) ? v0 : (i == 1) ? v1 : v2;
        float y = (vv - mean) * rstd * w[d] + b[d];
        if (OUTBF) outB[(size_t)row * D + d] = f2bf(y);
        else       outF[(size_t)row * D + d] = y;
    }
}

// ---- fused split-K reduce + bias + residual(h) + LayerNorm -> bf16 (or f32) ----
template <int S, bool OUTBF>
__global__ __launch_bounds__(256) void redln_kernel(const float* __restrict__ part,
                                                    const float* __restrict__ bias,
                                                    float* __restrict__ h,
                                                    const float* __restrict__ lnw,
                                                    const float* __restrict__ lnb,
                                                    ushort* __restrict__ outB,
                                                    float* __restrict__ outF) {
    __shared__ float red[2][4];
    int row = blockIdx.x;
    int t = threadIdx.x;
    float v[3];
    float s = 0.f, ss = 0.f;
#pragma unroll
    for (int i = 0; i < 3; ++i) {
        int d = t + i * 256;
        float x = h[(size_t)row * D + d] + bias[d];
#pragma unroll
        for (int sp = 0; sp < S; ++sp)
            x += part[((size_t)sp * L + row) * D + d];
        v[i] = x;
        h[(size_t)row * D + d] = x;
        s += x;
        ss += x * x;
    }
#pragma unroll
    for (int o = 32; o; o >>= 1) {
        s += __shfl_xor(s, o);
        ss += __shfl_xor(ss, o);
    }
    int wave = t >> 6;
    if ((t & 63) == 0) { red[0][wave] = s; red[1][wave] = ss; }
    __syncthreads();
    s = red[0][0] + red[0][1] + red[0][2] + red[0][3];
    ss = red[1][0] + red[1][1] + red[1][2] + red[1][3];
    float mean = s * (1.f / D);
    float var = ss * (1.f / D) - mean * mean;
    float rstd = rsqrtf(var + 1e-5f);
#pragma unroll
    for (int i = 0; i < 3; ++i) {
        int d = t + i * 256;
        float y = (v[i] - mean) * rstd * lnw[d] + lnb[d];
        if (OUTBF) outB[(size_t)row * D + d] = f2bf(y);
        else       outF[(size_t)row * D + d] = y;
    }
}

// ---------------- transpose-cast f32 [K][N] -> bf16 [N][K], z = layer ----------------
__global__ __launch_bounds__(256) void tcast_f32(const float* __restrict__ in,
                                                 ushort* __restrict__ out,
                                                 int K, int N,
                                                 size_t inStride, size_t outStride) {
    in += blockIdx.z * inStride;
    out += blockIdx.z * outStride;
    __shared__ float tile[64][65];
    int k0 = blockIdx.y * 64, n0 = blockIdx.x * 64;
    int t = threadIdx.x;
    int cl = t & 63, rg = t >> 6;
#pragma unroll
    for (int i = 0; i < 16; ++i) {
        int r = rg + 4 * i;
        tile[r][cl] = in[(size_t)(k0 + r) * N + n0 + cl];
    }
    __syncthreads();
#pragma unroll
    for (int i = 0; i < 16; ++i) {
        int r = rg + 4 * i;
        out[(size_t)(n0 + r) * K + k0 + cl] = f2bf(tile[cl][r]);
    }
}

// ---------------- bf16 MFMA GEMM, 128x128 tile, BK=32 ----------------
// VSPLIT: for the QKV GEMM, cols >= 2*D (the V projection) are written
// transposed into vTout[(col-2D)*L + row] instead of outB.
template <int ACT, bool OUTBF, int SPLITK, bool VSPLIT>
__global__ __launch_bounds__(256) void gemm_bf16(const ushort* __restrict__ A,
                                                 const ushort* __restrict__ Bt,
                                                 const float* __restrict__ bias,
                                                 const float* __restrict__ resid,
                                                 float* __restrict__ outF,
                                                 ushort* __restrict__ outB,
                                                 float* __restrict__ pout,
                                                 ushort* __restrict__ vTout,
                                                 int M, int N, int K) {
    __shared__ __align__(16) char lds[16384];
    char* Ab = lds;
    char* Bb = lds + 8192;
    const int tid = threadIdx.x;
    const int lane = tid & 63, w = tid >> 6;
    const int wr = w >> 1, wc = w & 1;
    const int bm = blockIdx.y * 128, bn = blockIdx.x * 128;
    const int l15 = lane & 15, l4 = lane >> 4;
    const int srow = tid >> 2, c = tid & 3;
    const int blo = (c & 1) * 32 + (c >> 1) * 8;
    const int kLen = K / SPLITK;
    const int kStart = (SPLITK > 1) ? blockIdx.z * kLen : 0;

    const int sxor = (srow & 3) << 4;
    const int wo0 = srow * 64 + (blo ^ sxor);
    const int wo1 = srow * 64 + ((blo + 16) ^ sxor);
    const int rxor = (l4 * 16) ^ ((l15 & 3) << 4);
    const int aBase = (wr * 64 + l15) * 64 + rxor;
    const int bBase = (wc * 64 + l15) * 64 + rxor;

    f32x4 acc[4][4];
#pragma unroll
    for (int m = 0; m < 4; ++m)
#pragma unroll
        for (int n = 0; n < 4; ++n)
            acc[m][n] = (f32x4){0.f, 0.f, 0.f, 0.f};

    const ushort* Ag = A + (size_t)(bm + srow) * K + kStart + c * 8;
    const ushort* Ag2 = Ag + (size_t)64 * K;
    const ushort* Bg = Bt + (size_t)(bn + srow) * K + kStart + c * 8;
    const ushort* Bg2 = Bg + (size_t)64 * K;

    for (int k0 = 0; k0 < kLen; k0 += 32) {
        uint4 a0 = *(const uint4*)(Ag + k0);
        uint4 a1 = *(const uint4*)(Ag2 + k0);
        uint4 b0 = *(const uint4*)(Bg + k0);
        uint4 b1 = *(const uint4*)(Bg2 + k0);
        uint2 t0, t1;
        t0.x = a0.x; t0.y = a0.y; t1.x = a0.z; t1.y = a0.w;
        *(uint2*)(Ab + wo0) = t0;
        *(uint2*)(Ab + wo1) = t1;
        t0.x = a1.x; t0.y = a1.y; t1.x = a1.z; t1.y = a1.w;
        *(uint2*)(Ab + wo0 + 4096) = t0;
        *(uint2*)(Ab + wo1 + 4096) = t1;
        t0.x = b0.x; t0.y = b0.y; t1.x = b0.z; t1.y = b0.w;
        *(uint2*)(Bb + wo0) = t0;
        *(uint2*)(Bb + wo1) = t1;
        t0.x = b1.x; t0.y = b1.y; t1.x = b1.z; t1.y = b1.w;
        *(uint2*)(Bb + wo0 + 4096) = t0;
        *(uint2*)(Bb + wo1 + 4096) = t1;
        __syncthreads();
        bf16x8 af[4], bfv[4];
#pragma unroll
        for (int m = 0; m < 4; ++m)
            af[m] = *(const bf16x8*)(Ab + aBase + m * 1024);
#pragma unroll
        for (int n = 0; n < 4; ++n)
            bfv[n] = *(const bf16x8*)(Bb + bBase + n * 1024);
#pragma unroll
        for (int m = 0; m < 4; ++m)
#pragma unroll
            for (int n = 0; n < 4; ++n)
                acc[m][n] = __builtin_amdgcn_mfma_f32_16x16x32_bf16(af[m], bfv[n], acc[m][n], 0, 0, 0);
        __syncthreads();
    }

    if (SPLITK > 1) {
        const size_t sb = (size_t)blockIdx.z * M;
#pragma unroll
        for (int m = 0; m < 4; ++m)
#pragma unroll
            for (int n = 0; n < 4; ++n) {
                int col = bn + wc * 64 + n * 16 + l15;
#pragma unroll
                for (int r = 0; r < 4; ++r) {
                    int row = bm + wr * 64 + m * 16 + l4 * 4 + r;
                    pout[(sb + row) * N + col] = acc[m][n][r];
                }
            }
    } else {
#pragma unroll
        for (int m = 0; m < 4; ++m)
#pragma unroll
            for (int n = 0; n < 4; ++n) {
                int col = bn + wc * 64 + n * 16 + l15;
                int row0 = bm + wr * 64 + m * 16 + l4 * 4;
                if (VSPLIT && col >= 2 * D) {
                    ushort4 pk;
                    pk.x = f2bf(acc[m][n][0]);
                    pk.y = f2bf(acc[m][n][1]);
                    pk.z = f2bf(acc[m][n][2]);
                    pk.w = f2bf(acc[m][n][3]);
                    *(ushort4*)(vTout + (size_t)(col - 2 * D) * L + row0) = pk;
                } else {
#pragma unroll
                    for (int r = 0; r < 4; ++r) {
                        int row = row0 + r;
                        float v = acc[m][n][r];
                        if (bias) v += bias[col];
                        if (ACT == 1) v = gelu_tanh(v);
                        if (resid) v += resid[(size_t)row * N + col];
                        if (OUTBF) outB[(size_t)row * N + col] = f2bf(v);
                        else       outF[(size_t)row * N + col] = v;
                    }
                }
            }
    }
}

// ---------------- MFMA flash attention, KVBLK=64, dbuf LDS, 1 barrier/tile ----
// LDS tile layout (K and V^T identical): row r (key / dh) at r*128B; within a
// row two 64B k-groups; fragment = one b128 at ((g*64 + l4*16) ^ ((r&7)<<4)).
__global__ __launch_bounds__(256) void attn_kernel(const ushort* __restrict__ qkv,
                                                   const ushort* __restrict__ vT,
                                                   const float* __restrict__ maskb,
                                                   ushort* __restrict__ ctx) {
    __shared__ __align__(16) char Kl[2][8192];
    __shared__ __align__(16) char Vl[2][8192];
    __shared__ float Ml[2][64];
    const int hh = blockIdx.y;
    const int q0 = ((int)gridDim.x - 1 - (int)blockIdx.x) * 64;  // long blocks first
    const int tid = threadIdx.x;
    const int lane = tid & 63, w = tid >> 6;
    const int l15 = lane & 15, l4 = lane >> 4;
    const int qg = q0 + w * 16 + l15;

    // Q fragments (B operand), from global
    bf16x8 qf[2];
#pragma unroll
    for (int ks = 0; ks < 2; ++ks)
        qf[ks] = ldfrag(qkv + (size_t)qg * QKVN + hh * 64 + ks * 32 + l4 * 4);

    f32x4 o[4];
#pragma unroll
    for (int i = 0; i < 4; ++i) o[i] = (f32x4){0.f, 0.f, 0.f, 0.f};
    float mrun = -1e30f, lrun = 0.f;

    // staging geometry
    const int srow = tid >> 2, c = tid & 3;
    const int blo = (c & 1) * 32 + (c >> 1) * 8;
    const int swz = (srow & 7) << 4;
    const int rb = srow * 128;
    const int lo4 = blo & 15;
    const int s0 = rb + (((blo)      & 0x70) ^ swz) + lo4;
    const int s1 = rb + (((blo + 16) & 0x70) ^ swz) + lo4;
    const int s2 = rb + (((blo + 64) & 0x70) ^ swz) + lo4;
    const int s3 = rb + (((blo + 80) & 0x70) ^ swz) + lo4;
    const int fxor = (l15 & 7) << 4;

    const ushort* Ksrc = qkv + (size_t)srow * QKVN + D + hh * 64 + c * 8;
    const ushort* Vsrc = vT + (size_t)(hh * 64 + srow) * L + c * 8;

    uint4 ka, kb, va, vb;
    float mv = 0.f;
    const int nt = q0 / 64 + 1;

    // prefetch tile 0
    {
        ka = *(const uint4*)(Ksrc);
        kb = *(const uint4*)(Ksrc + 32);
        va = *(const uint4*)(Vsrc);
        vb = *(const uint4*)(Vsrc + 32);
        if (tid < 64) mv = maskb[tid];
    }

    for (int it = 0; it < nt; ++it) {
        const int kv0 = it * 64;
        const int b = it & 1;
        // write staged regs -> LDS buffer b
        {
            char* Kb = Kl[b];
            char* Vb = Vl[b];
            uint2 t0, t1;
            t0.x = ka.x; t0.y = ka.y; t1.x = ka.z; t1.y = ka.w;
            *(uint2*)(Kb + s0) = t0;
            *(uint2*)(Kb + s1) = t1;
            t0.x = kb.x; t0.y = kb.y; t1.x = kb.z; t1.y = kb.w;
            *(uint2*)(Kb + s2) = t0;
            *(uint2*)(Kb + s3) = t1;
            t0.x = va.x; t0.y = va.y; t1.x = va.z; t1.y = va.w;
            *(uint2*)(Vb + s0) = t0;
            *(uint2*)(Vb + s1) = t1;
            t0.x = vb.x; t0.y = vb.y; t1.x = vb.z; t1.y = vb.w;
            *(uint2*)(Vb + s2) = t0;
            *(uint2*)(Vb + s3) = t1;
            if (tid < 64) Ml[b][tid] = mv;
        }
        __syncthreads();
        // issue next tile's global loads (latency hides under compute)
        if (it + 1 < nt) {
            const size_t koff = (size_t)(kv0 + 64) * QKVN;
            ka = *(const uint4*)(Ksrc + koff);
            kb = *(const uint4*)(Ksrc + koff + 32);
            va = *(const uint4*)(Vsrc + kv0 + 64);
            vb = *(const uint4*)(Vsrc + kv0 + 96);
            if (tid < 64) mv = maskb[kv0 + 64 + tid];
        }

        const char* Kb = Kl[b];
        const char* Vb = Vl[b];

        // S^T = K @ Q^T : rows = 64 keys (m=0..3), cols = 16 q
        f32x4 st[4];
#pragma unroll
        for (int m = 0; m < 4; ++m) st[m] = (f32x4){0.f, 0.f, 0.f, 0.f};
#pragma unroll
        for (int m = 0; m < 4; ++m)
#pragma unroll
            for (int ks = 0; ks < 2; ++ks) {
                bf16x8 kf = *(const bf16x8*)(Kb + (m * 16 + l15) * 128 +
                                             ((ks * 64 + l4 * 16) ^ fxor));
                st[m] = __builtin_amdgcn_mfma_f32_16x16x32_bf16(kf, qf[ks], st[m], 0, 0, 0);
            }

        // online softmax over 64 keys (16 per-lane values + cross-l4 reduce)
        float p[4][4];
        float tmax = -1e30f;
#pragma unroll
        for (int m = 0; m < 4; ++m)
#pragma unroll
            for (int r = 0; r < 4; ++r) {
                int kl = m * 16 + l4 * 4 + r;
                float s = st[m][r] + Ml[b][kl];
                if (kv0 + kl > qg) s = -1e30f;
                p[m][r] = s;
                tmax = fmaxf(tmax, s);
            }
        tmax = fmaxf(tmax, __shfl_xor(tmax, 16));
        tmax = fmaxf(tmax, __shfl_xor(tmax, 32));
        float mnew = fmaxf(mrun, tmax);
        float scale = __expf(mrun - mnew);
        float ts = 0.f;
#pragma unroll
        for (int m = 0; m < 4; ++m)
#pragma unroll
            for (int r = 0; r < 4; ++r) {
                float e = __expf(p[m][r] - mnew);
                p[m][r] = e;
                ts += e;
            }
        ts += __shfl_xor(ts, 16);
        ts += __shfl_xor(ts, 32);
        lrun = lrun * scale + ts;
        mrun = mnew;

        // P^T fragments (in-register): pf[g] covers keys g*32..g*32+31
        bf16x8 pf[2];
#pragma unroll
        for (int g = 0; g < 2; ++g)
#pragma unroll
            for (int r = 0; r < 4; ++r) {
                pf[g][r]     = (short)f2bf(p[2 * g][r]);
                pf[g][4 + r] = (short)f2bf(p[2 * g + 1][r]);
            }
#pragma unroll
        for (int i = 0; i < 4; ++i) {
            o[i][0] *= scale; o[i][1] *= scale; o[i][2] *= scale; o[i][3] *= scale;
        }
#pragma unroll
        for (int dhb = 0; dhb < 4; ++dhb)
#pragma unroll
            for (int g = 0; g < 2; ++g) {
                bf16x8 vf = *(const bf16x8*)(Vb + (dhb * 16 + l15) * 128 +
                                             ((g * 64 + l4 * 16) ^ fxor));
                o[dhb] = __builtin_amdgcn_mfma_f32_16x16x32_bf16(vf, pf[g], o[dhb], 0, 0, 0);
            }
    }

    float rinv = 1.0f / lrun;
#pragma unroll
    for (int dhb = 0; dhb < 4; ++dhb) {
        ushort4 pk;
        pk.x = f2bf(o[dhb][0] * rinv);
        pk.y = f2bf(o[dhb][1] * rinv);
        pk.z = f2bf(o[dhb][2] * rinv);
        pk.w = f2bf(o[dhb][3] * rinv);
        *(ushort4*)(ctx + (size_t)qg * D + hh * 64 + dhb * 16 + l4 * 4) = pk;
    }
}

extern "C" void kernel_launch(void* const* d_in, const int* in_sizes, int n_in,
                              void* d_out, int out_size, void* d_ws, size_t ws_size,
                              hipStream_t stream) {
    const int* ids = (const int*)d_in[0];
    const int* amask = (const int*)d_in[1];
    const float* wte = (const float*)d_in[2];
    const float* wpe = (const float*)d_in[3];
    const float* lnf_w = (const float*)d_in[4];
    const float* lnf_b = (const float*)d_in[5];
    const float* ln1_w = (const float*)d_in[6];
    const float* ln1_b = (const float*)d_in[7];
    const float* qw = (const float*)d_in[8];
    const float* kw = (const float*)d_in[9];
    const float* vw = (const float*)d_in[10];
    const float* ow = (const float*)d_in[11];
    const float* ob = (const float*)d_in[12];
    const float* ln2_w = (const float*)d_in[13];
    const float* ln2_b = (const float*)d_in[14];
    const float* fcw = (const float*)d_in[15];
    const float* fcb = (const float*)d_in[16];
    const float* pw = (const float*)d_in[17];
    const float* pb = (const float*)d_in[18];

    char* p = (char*)d_ws;
    auto take = [&](size_t bytes) -> char* {
        char* r = p;
        p += (bytes + 4095) & ~(size_t)4095;
        return r;
    };
    ushort* wqkvT = (ushort*)take((size_t)NL * QKVN * D * 2);
    ushort* woT   = (ushort*)take((size_t)NL * D * D * 2);
    ushort* fcwT  = (ushort*)take((size_t)NL * F * D * 2);
    ushort* pwT   = (ushort*)take((size_t)NL * D * F * 2);
    float*  h     = (float*)take((size_t)L * D * 4);
    ushort* xb    = (ushort*)take((size_t)L * D * 2);
    ushort* qkvb  = (ushort*)take((size_t)L * QKVN * 2);
    ushort* vTb   = (ushort*)take((size_t)D * L * 2);
    ushort* ctxb  = (ushort*)take((size_t)L * D * 2);
    ushort* f1b   = (ushort*)take((size_t)L * F * 2);
    float*  pk    = (float*)take((size_t)4 * L * D * 4);
    float*  mb    = (float*)take(L * 4);
    int*    pos   = (int*)take(L * 4);

    pos_kernel<<<8, 256, 0, stream>>>(amask, pos);
    maskb_kernel<<<8, 256, 0, stream>>>(amask, mb);
    embed_kernel<<<L, 256, 0, stream>>>(ids, pos, wte, wpe, h);

    tcast_f32<<<dim3(12, 12, NL), 256, 0, stream>>>(qw, wqkvT, D, D,
                                                    (size_t)D * D, (size_t)QKVN * D);
    tcast_f32<<<dim3(12, 12, NL), 256, 0, stream>>>(kw, wqkvT + (size_t)D * D, D, D,
                                                    (size_t)D * D, (size_t)QKVN * D);
    tcast_f32<<<dim3(12, 12, NL), 256, 0, stream>>>(vw, wqkvT + (size_t)2 * D * D, D, D,
                                                    (size_t)D * D, (size_t)QKVN * D);
    tcast_f32<<<dim3(12, 12, NL), 256, 0, stream>>>(ow, woT, D, D,
                                                    (size_t)D * D, (size_t)D * D);
    tcast_f32<<<dim3(48, 12, NL), 256, 0, stream>>>(fcw, fcwT, D, F,
                                                    (size_t)D * F, (size_t)F * D);
    tcast_f32<<<dim3(12, 48, NL), 256, 0, stream>>>(pw, pwT, F, D,
                                                    (size_t)F * D, (size_t)D * F);

    ln_kernel<true><<<L, 256, 0, stream>>>(h, ln1_w, ln1_b, nullptr, xb);

    for (int l = 0; l < NL; ++l) {
        gemm_bf16<0, true, 1, true><<<dim3(QKVN / 128, L / 128), 256, 0, stream>>>(
            xb, wqkvT + (size_t)l * QKVN * D, nullptr, nullptr, nullptr, qkvb, nullptr,
            vTb, L, QKVN, D);
        attn_kernel<<<dim3(L / 64, H), 256, 0, stream>>>(qkvb, vTb, mb, ctxb);
        gemm_bf16<0, true, 4, false><<<dim3(D / 128, L / 128, 4), 256, 0, stream>>>(
            ctxb, woT + (size_t)l * D * D, nullptr, nullptr, nullptr, nullptr, pk,
            nullptr, L, D, D);
        redln_kernel<4, true><<<L, 256, 0, stream>>>(
            pk, ob + l * D, h, ln2_w + l * D, ln2_b + l * D, xb, nullptr);
        gemm_bf16<1, true, 1, false><<<dim3(F / 128, L / 128), 256, 0, stream>>>(
            xb, fcwT + (size_t)l * F * D, fcb + l * F, nullptr, nullptr, f1b, nullptr,
            nullptr, L, F, D);
        gemm_bf16<0, true, 4, false><<<dim3(D / 128, L / 128, 4), 256, 0, stream>>>(
            f1b, pwT + (size_t)l * D * F, nullptr, nullptr, nullptr, nullptr, pk,
            nullptr, L, D, F);
        if (l < NL - 1) {
            redln_kernel<4, true><<<L, 256, 0, stream>>>(
                pk, pb + l * D, h, ln1_w + (l + 1) * D, ln1_b + (l + 1) * D, xb, nullptr);
        } else {
            redln_kernel<4, false><<<L, 256, 0, stream>>>(
                pk, pb + l * D, h, lnf_w, lnf_b, nullptr, (float*)d_out);
        }
    }
}

// Round 5
// 1919.284 us; speedup vs baseline: 16.7663x; 1.1459x over previous
//
#include <hip/hip_runtime.h>
#include <hip/hip_bf16.h>
#include <math.h>
#include <stdint.h>

#define L 2048
#define D 768
#define H 12
#define DH 64
#define F 3072
#define NL 12
#define QKVN 2304

typedef __attribute__((ext_vector_type(8))) short bf16x8;
typedef __attribute__((ext_vector_type(4))) float f32x4;

__device__ __forceinline__ ushort f2bf(float x) {
    union { float f; uint32_t u; } c; c.f = x;
    uint32_t r = c.u + 0x7FFFu + ((c.u >> 16) & 1u);
    return (ushort)(r >> 16);
}

// pack two f32 -> one dword of two bf16 (RNE), hardware packed convert
__device__ __forceinline__ uint32_t cvt_pk_bf16(float lo, float hi) {
    uint32_t r;
    asm("v_cvt_pk_bf16_f32 %0, %1, %2" : "=v"(r) : "v"(lo), "v"(hi));
    return r;
}

__device__ __forceinline__ bf16x8 ldfrag(const ushort* p) {
    ushort4 lo = *(const ushort4*)(p);
    ushort4 hi = *(const ushort4*)(p + 16);
    bf16x8 f;
    f[0] = (short)lo.x; f[1] = (short)lo.y; f[2] = (short)lo.z; f[3] = (short)lo.w;
    f[4] = (short)hi.x; f[5] = (short)hi.y; f[6] = (short)hi.z; f[7] = (short)hi.w;
    return f;
}

__device__ __forceinline__ float gelu_tanh(float x) {
    float c = 0.7978845608028654f;
    float inner = c * (x + 0.044715f * x * x * x);
    return 0.5f * x * (1.0f + tanhf(inner));
}

// ---------------- position cumsum ----------------
__global__ void pos_kernel(const int* __restrict__ mask, int* __restrict__ pos) {
    __shared__ int sm[L];
    for (int i = threadIdx.x; i < L; i += blockDim.x) sm[i] = mask[i];
    __syncthreads();
    int t = blockIdx.x * blockDim.x + threadIdx.x;
    if (t < L) {
        int s = 0;
        for (int j = 0; j <= t; ++j) s += sm[j];
        int p = s - 1;
        if (sm[t] == 0) p = 1;
        pos[t] = p;
    }
}

__global__ void maskb_kernel(const int* __restrict__ mask, float* __restrict__ mb) {
    int i = blockIdx.x * blockDim.x + threadIdx.x;
    if (i < L) mb[i] = mask[i] ? 0.f : -1e9f;
}

// ---------------- embedding ----------------
__global__ __launch_bounds__(256) void embed_kernel(const int* __restrict__ ids,
                                                    const int* __restrict__ pos,
                                                    const float* __restrict__ wte,
                                                    const float* __restrict__ wpe,
                                                    float* __restrict__ h) {
    int t = blockIdx.x;
    int id = ids[t];
    int p = pos[t];
    const float* we = wte + (size_t)id * D;
    const float* wp = wpe + (size_t)p * D;
    float* hr = h + (size_t)t * D;
#pragma unroll
    for (int i = 0; i < 3; ++i) {
        int d = threadIdx.x + i * 256;
        hr[d] = we[d] + wp[d];
    }
}

// ---------------- layernorm (f32 in, bf16 out) ----------------
template <bool OUTBF>
__global__ __launch_bounds__(256) void ln_kernel(const float* __restrict__ in,
                                                 const float* __restrict__ w,
                                                 const float* __restrict__ b,
                                                 float* __restrict__ outF,
                                                 ushort* __restrict__ outB) {
    __shared__ float red[2][4];
    int row = blockIdx.x;
    const float* x = in + (size_t)row * D;
    int t = threadIdx.x;
    float v0 = x[t], v1 = x[t + 256], v2 = x[t + 512];
    float s = v0 + v1 + v2;
    float ss = v0 * v0 + v1 * v1 + v2 * v2;
#pragma unroll
    for (int o = 32; o; o >>= 1) {
        s += __shfl_xor(s, o);
        ss += __shfl_xor(ss, o);
    }
    int wave = t >> 6;
    if ((t & 63) == 0) { red[0][wave] = s; red[1][wave] = ss; }
    __syncthreads();
    s = red[0][0] + red[0][1] + red[0][2] + red[0][3];
    ss = red[1][0] + red[1][1] + red[1][2] + red[1][3];
    float mean = s * (1.f / D);
    float var = ss * (1.f / D) - mean * mean;
    float rstd = rsqrtf(var + 1e-5f);
#pragma unroll
    for (int i = 0; i < 3; ++i) {
        int d = t + i * 256;
        float vv = (i == 0) ? v0 : (i == 1) ? v1 : v2;
        float y = (vv - mean) * rstd * w[d] + b[d];
        if (OUTBF) outB[(size_t)row * D + d] = f2bf(y);
        else       outF[(size_t)row * D + d] = y;
    }
}

// ---- fused split-K reduce + bias + residual(h) + LayerNorm -> bf16 (or f32) ----
template <int S, bool OUTBF>
__global__ __launch_bounds__(256) void redln_kernel(const float* __restrict__ part,
                                                    const float* __restrict__ bias,
                                                    float* __restrict__ h,
                                                    const float* __restrict__ lnw,
                                                    const float* __restrict__ lnb,
                                                    ushort* __restrict__ outB,
                                                    float* __restrict__ outF) {
    __shared__ float red[2][4];
    int row = blockIdx.x;
    int t = threadIdx.x;
    float v[3];
    float s = 0.f, ss = 0.f;
#pragma unroll
    for (int i = 0; i < 3; ++i) {
        int d = t + i * 256;
        float x = h[(size_t)row * D + d] + bias[d];
#pragma unroll
        for (int sp = 0; sp < S; ++sp)
            x += part[((size_t)sp * L + row) * D + d];
        v[i] = x;
        h[(size_t)row * D + d] = x;
        s += x;
        ss += x * x;
    }
#pragma unroll
    for (int o = 32; o; o >>= 1) {
        s += __shfl_xor(s, o);
        ss += __shfl_xor(ss, o);
    }
    int wave = t >> 6;
    if ((t & 63) == 0) { red[0][wave] = s; red[1][wave] = ss; }
    __syncthreads();
    s = red[0][0] + red[0][1] + red[0][2] + red[0][3];
    ss = red[1][0] + red[1][1] + red[1][2] + red[1][3];
    float mean = s * (1.f / D);
    float var = ss * (1.f / D) - mean * mean;
    float rstd = rsqrtf(var + 1e-5f);
#pragma unroll
    for (int i = 0; i < 3; ++i) {
        int d = t + i * 256;
        float y = (v[i] - mean) * rstd * lnw[d] + lnb[d];
        if (OUTBF) outB[(size_t)row * D + d] = f2bf(y);
        else       outF[(size_t)row * D + d] = y;
    }
}

// ---------------- transpose-cast f32 [K][N] -> bf16 [N][K], z = layer ----------------
__global__ __launch_bounds__(256) void tcast_f32(const float* __restrict__ in,
                                                 ushort* __restrict__ out,
                                                 int K, int N,
                                                 size_t inStride, size_t outStride) {
    in += blockIdx.z * inStride;
    out += blockIdx.z * outStride;
    __shared__ float tile[64][65];
    int k0 = blockIdx.y * 64, n0 = blockIdx.x * 64;
    int t = threadIdx.x;
    int cl = t & 63, rg = t >> 6;
#pragma unroll
    for (int i = 0; i < 16; ++i) {
        int r = rg + 4 * i;
        tile[r][cl] = in[(size_t)(k0 + r) * N + n0 + cl];
    }
    __syncthreads();
#pragma unroll
    for (int i = 0; i < 16; ++i) {
        int r = rg + 4 * i;
        out[(size_t)(n0 + r) * K + k0 + cl] = f2bf(tile[cl][r]);
    }
}

// ---------------- bf16 MFMA GEMM, 128x128 tile, BK=32, dbuf LDS, 1 barrier/step ----
// VSPLIT: for the QKV GEMM, cols >= 2*D (the V projection) are written
// transposed into vTout[(col-2D)*L + row] instead of outB.
template <int ACT, bool OUTBF, int SPLITK, bool VSPLIT>
__global__ __launch_bounds__(256) void gemm_bf16(const ushort* __restrict__ A,
                                                 const ushort* __restrict__ Bt,
                                                 const float* __restrict__ bias,
                                                 const float* __restrict__ resid,
                                                 float* __restrict__ outF,
                                                 ushort* __restrict__ outB,
                                                 float* __restrict__ pout,
                                                 ushort* __restrict__ vTout,
                                                 int M, int N, int K) {
    __shared__ __align__(16) char lds[32768];   // 2 x (A 8K + B 8K)
    const int tid = threadIdx.x;
    const int lane = tid & 63, w = tid >> 6;
    const int wr = w >> 1, wc = w & 1;
    const int bm = blockIdx.y * 128, bn = blockIdx.x * 128;
    const int l15 = lane & 15, l4 = lane >> 4;
    const int srow = tid >> 2, c = tid & 3;
    const int blo = (c & 1) * 32 + (c >> 1) * 8;
    const int kLen = K / SPLITK;
    const int kStart = (SPLITK > 1) ? blockIdx.z * kLen : 0;

    const int sxor = (srow & 3) << 4;
    const int wo0 = srow * 64 + (blo ^ sxor);
    const int wo1 = srow * 64 + ((blo + 16) ^ sxor);
    const int rxor = (l4 * 16) ^ ((l15 & 3) << 4);
    const int aBase = (wr * 64 + l15) * 64 + rxor;
    const int bBase = (wc * 64 + l15) * 64 + rxor;

    f32x4 acc[4][4];
#pragma unroll
    for (int m = 0; m < 4; ++m)
#pragma unroll
        for (int n = 0; n < 4; ++n)
            acc[m][n] = (f32x4){0.f, 0.f, 0.f, 0.f};

    const ushort* Ag = A + (size_t)(bm + srow) * K + kStart + c * 8;
    const ushort* Ag2 = Ag + (size_t)64 * K;
    const ushort* Bg = Bt + (size_t)(bn + srow) * K + kStart + c * 8;
    const ushort* Bg2 = Bg + (size_t)64 * K;

    // prefetch step 0
    uint4 a0 = *(const uint4*)(Ag);
    uint4 a1 = *(const uint4*)(Ag2);
    uint4 b0 = *(const uint4*)(Bg);
    uint4 b1 = *(const uint4*)(Bg2);

    for (int k0 = 0; k0 < kLen; k0 += 32) {
        char* Ab = lds + ((k0 >> 5) & 1) * 16384;
        char* Bb = Ab + 8192;
        uint2 t0, t1;
        t0.x = a0.x; t0.y = a0.y; t1.x = a0.z; t1.y = a0.w;
        *(uint2*)(Ab + wo0) = t0;
        *(uint2*)(Ab + wo1) = t1;
        t0.x = a1.x; t0.y = a1.y; t1.x = a1.z; t1.y = a1.w;
        *(uint2*)(Ab + wo0 + 4096) = t0;
        *(uint2*)(Ab + wo1 + 4096) = t1;
        t0.x = b0.x; t0.y = b0.y; t1.x = b0.z; t1.y = b0.w;
        *(uint2*)(Bb + wo0) = t0;
        *(uint2*)(Bb + wo1) = t1;
        t0.x = b1.x; t0.y = b1.y; t1.x = b1.z; t1.y = b1.w;
        *(uint2*)(Bb + wo0 + 4096) = t0;
        *(uint2*)(Bb + wo1 + 4096) = t1;
        __syncthreads();
        // issue next step's global loads; they complete under this step's MFMAs
        if (k0 + 32 < kLen) {
            a0 = *(const uint4*)(Ag + k0 + 32);
            a1 = *(const uint4*)(Ag2 + k0 + 32);
            b0 = *(const uint4*)(Bg + k0 + 32);
            b1 = *(const uint4*)(Bg2 + k0 + 32);
        }
        bf16x8 af[4], bfv[4];
#pragma unroll
        for (int m = 0; m < 4; ++m)
            af[m] = *(const bf16x8*)(Ab + aBase + m * 1024);
#pragma unroll
        for (int n = 0; n < 4; ++n)
            bfv[n] = *(const bf16x8*)(Bb + bBase + n * 1024);
#pragma unroll
        for (int m = 0; m < 4; ++m)
#pragma unroll
            for (int n = 0; n < 4; ++n)
                acc[m][n] = __builtin_amdgcn_mfma_f32_16x16x32_bf16(af[m], bfv[n], acc[m][n], 0, 0, 0);
        // no trailing barrier: next iter writes the OTHER buffer; the barrier at
        // the top of the next iter orders reads of this buffer vs its next write.
    }

    if (SPLITK > 1) {
        const size_t sb = (size_t)blockIdx.z * M;
#pragma unroll
        for (int m = 0; m < 4; ++m)
#pragma unroll
            for (int n = 0; n < 4; ++n) {
                int col = bn + wc * 64 + n * 16 + l15;
#pragma unroll
                for (int r = 0; r < 4; ++r) {
                    int row = bm + wr * 64 + m * 16 + l4 * 4 + r;
                    pout[(sb + row) * N + col] = acc[m][n][r];
                }
            }
    } else {
#pragma unroll
        for (int m = 0; m < 4; ++m)
#pragma unroll
            for (int n = 0; n < 4; ++n) {
                int col = bn + wc * 64 + n * 16 + l15;
                int row0 = bm + wr * 64 + m * 16 + l4 * 4;
                if (VSPLIT && col >= 2 * D) {
                    ushort4 pk;
                    pk.x = f2bf(acc[m][n][0]);
                    pk.y = f2bf(acc[m][n][1]);
                    pk.z = f2bf(acc[m][n][2]);
                    pk.w = f2bf(acc[m][n][3]);
                    *(ushort4*)(vTout + (size_t)(col - 2 * D) * L + row0) = pk;
                } else {
#pragma unroll
                    for (int r = 0; r < 4; ++r) {
                        int row = row0 + r;
                        float v = acc[m][n][r];
                        if (bias) v += bias[col];
                        if (ACT == 1) v = gelu_tanh(v);
                        if (resid) v += resid[(size_t)row * N + col];
                        if (OUTBF) outB[(size_t)row * N + col] = f2bf(v);
                        else       outF[(size_t)row * N + col] = v;
                    }
                }
            }
    }
}

// ---------------- MFMA flash attention, KVBLK=64, dbuf LDS, 1 barrier/tile ----
__global__ __launch_bounds__(256) void attn_kernel(const ushort* __restrict__ qkv,
                                                   const ushort* __restrict__ vT,
                                                   const float* __restrict__ maskb,
                                                   ushort* __restrict__ ctx) {
    __shared__ __align__(16) char Kl[2][8192];
    __shared__ __align__(16) char Vl[2][8192];
    __shared__ float Ml[2][64];
    const int hh = blockIdx.y;
    const int q0 = ((int)gridDim.x - 1 - (int)blockIdx.x) * 64;  // long blocks first
    const int tid = threadIdx.x;
    const int lane = tid & 63, w = tid >> 6;
    const int l15 = lane & 15, l4 = lane >> 4;
    const int qg = q0 + w * 16 + l15;
    const int qmin = q0 + w * 16;   // wave-uniform

    bf16x8 qf[2];
#pragma unroll
    for (int ks = 0; ks < 2; ++ks)
        qf[ks] = ldfrag(qkv + (size_t)qg * QKVN + hh * 64 + ks * 32 + l4 * 4);

    f32x4 o[4];
#pragma unroll
    for (int i = 0; i < 4; ++i) o[i] = (f32x4){0.f, 0.f, 0.f, 0.f};
    float mrun = -1e30f, lrun = 0.f;

    const int srow = tid >> 2, c = tid & 3;
    const int blo = (c & 1) * 32 + (c >> 1) * 8;
    const int swz = (srow & 7) << 4;
    const int rb = srow * 128;
    const int lo4 = blo & 15;
    const int s0 = rb + (((blo)      & 0x70) ^ swz) + lo4;
    const int s1 = rb + (((blo + 16) & 0x70) ^ swz) + lo4;
    const int s2 = rb + (((blo + 64) & 0x70) ^ swz) + lo4;
    const int s3 = rb + (((blo + 80) & 0x70) ^ swz) + lo4;
    const int fxor = (l15 & 7) << 4;

    const ushort* Ksrc = qkv + (size_t)srow * QKVN + D + hh * 64 + c * 8;
    const ushort* Vsrc = vT + (size_t)(hh * 64 + srow) * L + c * 8;

    uint4 ka, kb, va, vb;
    float mv = 0.f;
    const int nt = q0 / 64 + 1;

    {
        ka = *(const uint4*)(Ksrc);
        kb = *(const uint4*)(Ksrc + 32);
        va = *(const uint4*)(Vsrc);
        vb = *(const uint4*)(Vsrc + 32);
        if (tid < 64) mv = maskb[tid];
    }

    for (int it = 0; it < nt; ++it) {
        const int kv0 = it * 64;
        const int b = it & 1;
        {
            char* Kb = Kl[b];
            char* Vb = Vl[b];
            uint2 t0, t1;
            t0.x = ka.x; t0.y = ka.y; t1.x = ka.z; t1.y = ka.w;
            *(uint2*)(Kb + s0) = t0;
            *(uint2*)(Kb + s1) = t1;
            t0.x = kb.x; t0.y = kb.y; t1.x = kb.z; t1.y = kb.w;
            *(uint2*)(Kb + s2) = t0;
            *(uint2*)(Kb + s3) = t1;
            t0.x = va.x; t0.y = va.y; t1.x = va.z; t1.y = va.w;
            *(uint2*)(Vb + s0) = t0;
            *(uint2*)(Vb + s1) = t1;
            t0.x = vb.x; t0.y = vb.y; t1.x = vb.z; t1.y = vb.w;
            *(uint2*)(Vb + s2) = t0;
            *(uint2*)(Vb + s3) = t1;
            if (tid < 64) Ml[b][tid] = mv;
        }
        __syncthreads();
        if (it + 1 < nt) {
            const size_t koff = (size_t)(kv0 + 64) * QKVN;
            ka = *(const uint4*)(Ksrc + koff);
            kb = *(const uint4*)(Ksrc + koff + 32);
            va = *(const uint4*)(Vsrc + kv0 + 64);
            vb = *(const uint4*)(Vsrc + kv0 + 96);
            if (tid < 64) mv = maskb[kv0 + 64 + tid];
        }

        const char* Kb = Kl[b];
        const char* Vb = Vl[b];

        f32x4 st[4];
#pragma unroll
        for (int m = 0; m < 4; ++m) st[m] = (f32x4){0.f, 0.f, 0.f, 0.f};
#pragma unroll
        for (int m = 0; m < 4; ++m)
#pragma unroll
            for (int ks = 0; ks < 2; ++ks) {
                bf16x8 kf = *(const bf16x8*)(Kb + (m * 16 + l15) * 128 +
                                             ((ks * 64 + l4 * 16) ^ fxor));
                st[m] = __builtin_amdgcn_mfma_f32_16x16x32_bf16(kf, qf[ks], st[m], 0, 0, 0);
            }

        float p[4][4];
        float tmax = -1e30f;
        const bool full = (kv0 + 63 <= qmin);   // wave-uniform: no causal clamp needed
        if (full) {
#pragma unroll
            for (int m = 0; m < 4; ++m)
#pragma unroll
                for (int r = 0; r < 4; ++r) {
                    int kl = m * 16 + l4 * 4 + r;
                    float s = st[m][r] + Ml[b][kl];
                    p[m][r] = s;
                    tmax = fmaxf(tmax, s);
                }
        } else {
#pragma unroll
            for (int m = 0; m < 4; ++m)
#pragma unroll
                for (int r = 0; r < 4; ++r) {
                    int kl = m * 16 + l4 * 4 + r;
                    float s = st[m][r] + Ml[b][kl];
                    if (kv0 + kl > qg) s = -1e30f;
                    p[m][r] = s;
                    tmax = fmaxf(tmax, s);
                }
        }
        tmax = fmaxf(tmax, __shfl_xor(tmax, 16));
        tmax = fmaxf(tmax, __shfl_xor(tmax, 32));
        const bool noresc = __all(tmax <= mrun);   // T13 defer-rescale, exact
        float mnew = noresc ? mrun : fmaxf(mrun, tmax);
        float scale = noresc ? 1.f : __expf(mrun - mnew);
        float ts = 0.f;
#pragma unroll
        for (int m = 0; m < 4; ++m)
#pragma unroll
            for (int r = 0; r < 4; ++r) {
                float e = __expf(p[m][r] - mnew);
                p[m][r] = e;
                ts += e;
            }
        ts += __shfl_xor(ts, 16);
        ts += __shfl_xor(ts, 32);
        lrun = lrun * scale + ts;
        mrun = mnew;

        // pack P^T fragments with packed bf16 converts (8 instrs vs 48)
        bf16x8 pf[2];
#pragma unroll
        for (int g = 0; g < 2; ++g) {
            union { bf16x8 v; uint32_t d[4]; } pu;
            pu.d[0] = cvt_pk_bf16(p[2 * g][0], p[2 * g][1]);
            pu.d[1] = cvt_pk_bf16(p[2 * g][2], p[2 * g][3]);
            pu.d[2] = cvt_pk_bf16(p[2 * g + 1][0], p[2 * g + 1][1]);
            pu.d[3] = cvt_pk_bf16(p[2 * g + 1][2], p[2 * g + 1][3]);
            pf[g] = pu.v;
        }
        if (!noresc) {
#pragma unroll
            for (int i = 0; i < 4; ++i) {
                o[i][0] *= scale; o[i][1] *= scale; o[i][2] *= scale; o[i][3] *= scale;
            }
        }
#pragma unroll
        for (int dhb = 0; dhb < 4; ++dhb)
#pragma unroll
            for (int g = 0; g < 2; ++g) {
                bf16x8 vf = *(const bf16x8*)(Vb + (dhb * 16 + l15) * 128 +
                                             ((g * 64 + l4 * 16) ^ fxor));
                o[dhb] = __builtin_amdgcn_mfma_f32_16x16x32_bf16(vf, pf[g], o[dhb], 0, 0, 0);
            }
    }

    float rinv = 1.0f / lrun;
#pragma unroll
    for (int dhb = 0; dhb < 4; ++dhb) {
        ushort4 pk;
        pk.x = f2bf(o[dhb][0] * rinv);
        pk.y = f2bf(o[dhb][1] * rinv);
        pk.z = f2bf(o[dhb][2] * rinv);
        pk.w = f2bf(o[dhb][3] * rinv);
        *(ushort4*)(ctx + (size_t)qg * D + hh * 64 + dhb * 16 + l4 * 4) = pk;
    }
}

extern "C" void kernel_launch(void* const* d_in, const int* in_sizes, int n_in,
                              void* d_out, int out_size, void* d_ws, size_t ws_size,
                              hipStream_t stream) {
    const int* ids = (const int*)d_in[0];
    const int* amask = (const int*)d_in[1];
    const float* wte = (const float*)d_in[2];
    const float* wpe = (const float*)d_in[3];
    const float* lnf_w = (const float*)d_in[4];
    const float* lnf_b = (const float*)d_in[5];
    const float* ln1_w = (const float*)d_in[6];
    const float* ln1_b = (const float*)d_in[7];
    const float* qw = (const float*)d_in[8];
    const float* kw = (const float*)d_in[9];
    const float* vw = (const float*)d_in[10];
    const float* ow = (const float*)d_in[11];
    const float* ob = (const float*)d_in[12];
    const float* ln2_w = (const float*)d_in[13];
    const float* ln2_b = (const float*)d_in[14];
    const float* fcw = (const float*)d_in[15];
    const float* fcb = (const float*)d_in[16];
    const float* pw = (const float*)d_in[17];
    const float* pb = (const float*)d_in[18];

    char* p = (char*)d_ws;
    auto take = [&](size_t bytes) -> char* {
        char* r = p;
        p += (bytes + 4095) & ~(size_t)4095;
        return r;
    };
    ushort* wqkvT = (ushort*)take((size_t)NL * QKVN * D * 2);
    ushort* woT   = (ushort*)take((size_t)NL * D * D * 2);
    ushort* fcwT  = (ushort*)take((size_t)NL * F * D * 2);
    ushort* pwT   = (ushort*)take((size_t)NL * D * F * 2);
    float*  h     = (float*)take((size_t)L * D * 4);
    ushort* xb    = (ushort*)take((size_t)L * D * 2);
    ushort* qkvb  = (ushort*)take((size_t)L * QKVN * 2);
    ushort* vTb   = (ushort*)take((size_t)D * L * 2);
    ushort* ctxb  = (ushort*)take((size_t)L * D * 2);
    ushort* f1b   = (ushort*)take((size_t)L * F * 2);
    float*  pk    = (float*)take((size_t)4 * L * D * 4);
    float*  mb    = (float*)take(L * 4);
    int*    pos   = (int*)take(L * 4);

    pos_kernel<<<8, 256, 0, stream>>>(amask, pos);
    maskb_kernel<<<8, 256, 0, stream>>>(amask, mb);
    embed_kernel<<<L, 256, 0, stream>>>(ids, pos, wte, wpe, h);

    tcast_f32<<<dim3(12, 12, NL), 256, 0, stream>>>(qw, wqkvT, D, D,
                                                    (size_t)D * D, (size_t)QKVN * D);
    tcast_f32<<<dim3(12, 12, NL), 256, 0, stream>>>(kw, wqkvT + (size_t)D * D, D, D,
                                                    (size_t)D * D, (size_t)QKVN * D);
    tcast_f32<<<dim3(12, 12, NL), 256, 0, stream>>>(vw, wqkvT + (size_t)2 * D * D, D, D,
                                                    (size_t)D * D, (size_t)QKVN * D);
    tcast_f32<<<dim3(12, 12, NL), 256, 0, stream>>>(ow, woT, D, D,
                                                    (size_t)D * D, (size_t)D * D);
    tcast_f32<<<dim3(48, 12, NL), 256, 0, stream>>>(fcw, fcwT, D, F,
                                                    (size_t)D * F, (size_t)F * D);
    tcast_f32<<<dim3(12, 48, NL), 256, 0, stream>>>(pw, pwT, F, D,
                                                    (size_t)F * D, (size_t)D * F);

    ln_kernel<true><<<L, 256, 0, stream>>>(h, ln1_w, ln1_b, nullptr, xb);

    for (int l = 0; l < NL; ++l) {
        gemm_bf16<0, true, 1, true><<<dim3(QKVN / 128, L / 128), 256, 0, stream>>>(
            xb, wqkvT + (size_t)l * QKVN * D, nullptr, nullptr, nullptr, qkvb, nullptr,
            vTb, L, QKVN, D);
        attn_kernel<<<dim3(L / 64, H), 256, 0, stream>>>(qkvb, vTb, mb, ctxb);
        gemm_bf16<0, true, 4, false><<<dim3(D / 128, L / 128, 4), 256, 0, stream>>>(
            ctxb, woT + (size_t)l * D * D, nullptr, nullptr, nullptr, nullptr, pk,
            nullptr, L, D, D);
        redln_kernel<4, true><<<L, 256, 0, stream>>>(
            pk, ob + l * D, h, ln2_w + l * D, ln2_b + l * D, xb, nullptr);
        gemm_bf16<1, true, 1, false><<<dim3(F / 128, L / 128), 256, 0, stream>>>(
            xb, fcwT + (size_t)l * F * D, fcb + l * F, nullptr, nullptr, f1b, nullptr,
            nullptr, L, F, D);
        gemm_bf16<0, true, 4, false><<<dim3(D / 128, L / 128, 4), 256, 0, stream>>>(
            f1b, pwT + (size_t)l * D * F, nullptr, nullptr, nullptr, nullptr, pk,
            nullptr, L, D, F);
        if (l < NL - 1) {
            redln_kernel<4, true><<<L, 256, 0, stream>>>(
                pk, pb + l * D, h, ln1_w + (l + 1) * D, ln1_b + (l + 1) * D, xb, nullptr);
        } else {
            redln_kernel<4, false><<<L, 256, 0, stream>>>(
                pk, pb + l * D, h, lnf_w, lnf_b, nullptr, (float*)d_out);
        }
    }
}